// Round 9
// baseline (351.157 us; speedup 1.0000x reference)
//
#include <hip/hip_runtime.h>
#include <hip/hip_bf16.h>

typedef _Float16 half8 __attribute__((ext_vector_type(8)));
typedef _Float16 half4 __attribute__((ext_vector_type(4)));
typedef _Float16 half2t __attribute__((ext_vector_type(2)));
typedef float floatx4 __attribute__((ext_vector_type(4)));
typedef float floatx16 __attribute__((ext_vector_type(16)));
typedef unsigned int uint2v __attribute__((ext_vector_type(2)));

#define LOG2E 1.44269504088896340736f

__device__ __forceinline__ half8 cvt8r(floatx4 a, floatx4 b) {
    half8 h;
    h[0] = (_Float16)a[0]; h[1] = (_Float16)a[1]; h[2] = (_Float16)a[2]; h[3] = (_Float16)a[3];
    h[4] = (_Float16)b[0]; h[5] = (_Float16)b[1]; h[6] = (_Float16)b[2]; h[7] = (_Float16)b[3];
    return h;
}

union H8U { half8 h; half2t v2[4]; uint2v u[2]; };

// ---------------- K1: transpose + convert W (f32 [512x512]) -> WT fp16 [n][k] ----------------
__global__ __launch_bounds__(256) void transpose_w_kernel(
        const float* __restrict__ Wq, const float* __restrict__ Wk,
        const float* __restrict__ Wv, const float* __restrict__ Wo,
        _Float16* __restrict__ out) {
    const float* W = (blockIdx.z == 0) ? Wq : (blockIdx.z == 1) ? Wk : (blockIdx.z == 2) ? Wv : Wo;
    _Float16* o = out + (size_t)blockIdx.z * 512 * 512;
    __shared__ __align__(16) _Float16 t[64][72];
    int r0 = blockIdx.x * 64, c0 = blockIdx.y * 64;
    int tid = threadIdx.x;
    for (int i = 0; i < 2; i++) {
        int f = i * 256 + tid;
        int row = f >> 3, seg = f & 7;
        const float* p = W + (size_t)(r0 + row) * 512 + c0 + seg * 8;
        *(half8*)&t[row][seg * 8] = cvt8r(*(const floatx4*)p, *(const floatx4*)(p + 4));
    }
    __syncthreads();
    for (int i = 0; i < 2; i++) {
        int f = i * 256 + tid;
        int crow = f >> 3, seg = f & 7;
        half8 hv;
        for (int j = 0; j < 8; j++) hv[j] = t[seg * 8 + j][crow];
        *(half8*)(o + (size_t)(c0 + crow) * 512 + r0 + seg * 8) = hv;
    }
}

// ---------------- K2: QKV projection GEMM, 64x128 tiles; dead K/V blocks skipped ----------------
__global__ __launch_bounds__(256) void gemm_qkv_kernel(
        const float* __restrict__ Xq, const float* __restrict__ Xk, const float* __restrict__ Xv,
        const _Float16* __restrict__ WTall,
        const float* __restrict__ bq, const float* __restrict__ bk, const float* __restrict__ bv,
        const int* __restrict__ vlens,
        _Float16* __restrict__ qo, _Float16* __restrict__ ko2, _Float16* __restrict__ vto) {
    int z = blockIdx.z;
    int mBase = blockIdx.x * 64, nBase = blockIdx.y * 128;

    if (z >= 1) {
        int b_ = mBase >> 11, s0 = mBase & 2047;
        int L = vlens[b_];
        if (s0 >= L && !(z == 2 && L == 0)) return;
    }

    const float* X = (z == 0) ? Xq : (z == 1) ? Xk : Xv;
    const _Float16* BT = WTall + (size_t)z * 512 * 512;
    const float* bias = (z == 0) ? bq : (z == 1) ? bk : bv;

    __shared__ __align__(16) _Float16 Asm[64][72];
    __shared__ __align__(16) _Float16 Bsm[128][72];

    int tid = threadIdx.x;
    int wave = tid >> 6, lane = tid & 63;
    int lrow = lane & 15, quad = lane >> 4;
    int mrow = wave * 16 + lrow;

    const floatx4 fz = {0.f, 0.f, 0.f, 0.f};
    floatx4 acc[8];
    for (int i = 0; i < 8; i++) acc[i] = fz;

    int arow[2], aseg[2], brow[4], bseg[4];
    for (int i = 0; i < 2; i++) { int f = i * 256 + tid; arow[i] = f >> 3; aseg[i] = f & 7; }
    for (int i = 0; i < 4; i++) { int f = i * 256 + tid; brow[i] = f >> 3; bseg[i] = f & 7; }

    floatx4 areg[2][2];
    half8 breg[4];
    for (int i = 0; i < 2; i++) {
        const float* pa = X + (size_t)(mBase + arow[i]) * 512 + aseg[i] * 8;
        areg[i][0] = *(const floatx4*)pa;
        areg[i][1] = *(const floatx4*)(pa + 4);
    }
    for (int i = 0; i < 4; i++)
        breg[i] = *(const half8*)(BT + (size_t)(nBase + brow[i]) * 512 + bseg[i] * 8);

    for (int kb = 0; kb < 512; kb += 64) {
        for (int i = 0; i < 2; i++) *(half8*)&Asm[arow[i]][aseg[i] * 8] = cvt8r(areg[i][0], areg[i][1]);
        for (int i = 0; i < 4; i++) *(half8*)&Bsm[brow[i]][bseg[i] * 8] = breg[i];
        __syncthreads();
        if (kb + 64 < 512) {
            int kn = kb + 64;
            for (int i = 0; i < 2; i++) {
                const float* pa = X + (size_t)(mBase + arow[i]) * 512 + kn + aseg[i] * 8;
                areg[i][0] = *(const floatx4*)pa;
                areg[i][1] = *(const floatx4*)(pa + 4);
            }
            for (int i = 0; i < 4; i++)
                breg[i] = *(const half8*)(BT + (size_t)(nBase + brow[i]) * 512 + kn + bseg[i] * 8);
        }
        for (int kc = 0; kc < 2; kc++) {
            int ko_ = kc * 32 + quad * 8;
            half8 a = *(const half8*)&Asm[mrow][ko_];
            for (int nt = 0; nt < 8; nt++) {
                half8 b = *(const half8*)&Bsm[nt * 16 + lrow][ko_];
                acc[nt] = __builtin_amdgcn_mfma_f32_16x16x32_f16(a, b, acc[nt], 0, 0, 0);
            }
        }
        __syncthreads();
    }

    if (z == 2) {
        for (int nt = 0; nt < 8; nt++) {
            int gc = nBase + nt * 16 + lrow;
            float bb = bias[gc];
            int h = gc >> 6, hd = gc & 63;
            int gr = mBase + wave * 16 + quad * 4;
            int b_ = gr >> 11, s = gr & 2047;
            half4 hv;
            for (int r = 0; r < 4; r++) hv[r] = (_Float16)(acc[nt][r] + bb);
            *(half4*)(vto + (((size_t)(b_ * 8 + h) * 64 + hd) * 2048 + s)) = hv;
        }
    } else {
        _Float16* out = (z == 0) ? qo : ko2;
        for (int nt = 0; nt < 8; nt++) {
            int gc = nBase + nt * 16 + lrow;
            float bb = bias[gc];
            int h = gc >> 6, hd = gc & 63;
            for (int r = 0; r < 4; r++) {
                int gr = mBase + wave * 16 + quad * 4 + r;
                int b_ = gr >> 11, s = gr & 2047;
                out[(((size_t)b_ * 8 + h) * 2048 + s) * 64 + hd] = (_Float16)(acc[nt][r] + bb);
            }
        }
    }
}

// ---------------- K3: flash attention (r7 frozen): BM=64, 4 waves (2 wq x 2 ks) ----------------
__global__ __launch_bounds__(256) void attn_kernel(
        const _Float16* __restrict__ qws, const _Float16* __restrict__ kws,
        const _Float16* __restrict__ vtws, const int* __restrict__ vlens,
        _Float16* __restrict__ aout) {
    int idx = blockIdx.x;
    int b = ((idx & 3) + (idx >> 8)) & 3;
    int h = (idx >> 2) & 7;
    int q0 = ((idx >> 5) & 31) * 64;
    int bh = b * 8 + h;
    int L = vlens[b];
    bool uni = (L == 0);
    int nkt = uni ? 32 : ((L + 63) >> 6);
    int nfull = uni ? 0 : (L >> 6);

    int tid = threadIdx.x;
    int wid = tid >> 6;
    int wq = wid & 1, ks = wid >> 1;
    int lane = tid & 63;
    int l31 = lane & 31, hi = lane >> 5;

    __shared__ __align__(16) _Float16 ksm[2][64 * 64];
    __shared__ __align__(16) _Float16 vtsm[2][64 * 64];

    const _Float16* kbase = kws + (size_t)bh * 2048 * 64;
    const _Float16* vtbase = vtws + (size_t)bh * 64 * 2048;

    half8 qf[4];
    {
        const _Float16* qrow = qws + ((size_t)bh * 2048 + q0 + wq * 32 + l31) * 64;
#pragma unroll
        for (int kc = 0; kc < 4; kc++) {
            qf[kc] = *(const half8*)(qrow + kc * 16 + hi * 8);
            qf[kc] = qf[kc] * (_Float16)(0.125f * LOG2E);
        }
    }

    floatx16 oacc0, oacc1;
#pragma unroll
    for (int i = 0; i < 16; i++) { oacc0[i] = 0.f; oacc1[i] = 0.f; }
    float rs = 0.f;

    int htid = tid & 127;
    int tt = tid >> 7;
    int seg = htid & 7;
    int trow = htid >> 3;
    int xr = (l31 & 15) << 3;
    char* ksmB = (char*)&ksm[tt][0];
    char* vsmB = (char*)&vtsm[tt][0];

    half8 kreg[4], vreg[4];
    if (tt < nkt) {
        const _Float16* kp = kbase + (size_t)tt * 4096;
        const _Float16* vp = vtbase + tt * 64;
#pragma unroll
        for (int i = 0; i < 4; i++) {
            int row = i * 16 + trow;
            kreg[i] = *(const half8*)(kp + row * 64 + seg * 8);
            vreg[i] = *(const half8*)(vp + (size_t)row * 2048 + seg * 8);
        }
    }

    for (int kt2 = 0; kt2 < nkt; kt2 += 2) {
        if (kt2 + tt < nkt) {
#pragma unroll
            for (int i = 0; i < 4; i++) {
                int row = i * 16 + trow;
                int wo = row * 128 + ((seg * 16) ^ ((row & 15) << 3));
                H8U kv, vv;
                kv.h = kreg[i]; vv.h = vreg[i];
                *(uint2v*)(ksmB + wo) = kv.u[0];
                *(uint2v*)(ksmB + (wo ^ 8)) = kv.u[1];
                *(uint2v*)(vsmB + wo) = vv.u[0];
                *(uint2v*)(vsmB + (wo ^ 8)) = vv.u[1];
            }
        }
        __syncthreads();
        int nxt = kt2 + 2 + tt;
        if (nxt < nkt) {
            const _Float16* kp = kbase + (size_t)nxt * 4096;
            const _Float16* vp = vtbase + nxt * 64;
#pragma unroll
            for (int i = 0; i < 4; i++) {
                int row = i * 16 + trow;
                kreg[i] = *(const half8*)(kp + row * 64 + seg * 8);
                vreg[i] = *(const half8*)(vp + (size_t)row * 2048 + seg * 8);
            }
        }

        int kt = kt2 + ks;
        if (kt < nkt) {
#pragma unroll
            for (int t = 0; t < 2; t++) {
                floatx16 sacc;
#pragma unroll
                for (int i = 0; i < 16; i++) sacc[i] = 0.f;
                int rbase = (t * 32 + l31) * 128;
#pragma unroll
                for (int kc = 0; kc < 4; kc++) {
                    int off = rbase + ((kc * 32 + hi * 16) ^ xr);
                    H8U kf;
                    kf.u[0] = *(const uint2v*)(ksmB + off);
                    kf.u[1] = *(const uint2v*)(ksmB + (off ^ 8));
                    sacc = __builtin_amdgcn_mfma_f32_32x32x16_f16(kf.h, qf[kc], sacc, 0, 0, 0);
                }

                float p[16];
                if (kt < nfull) {
#pragma unroll
                    for (int r = 0; r < 16; r++) p[r] = exp2f(sacc[r]);
                } else {
                    int kb0 = kt * 64 + t * 32 + 4 * hi;
#pragma unroll
                    for (int r = 0; r < 16; r++) {
                        int key = kb0 + (r & 3) + 8 * (r >> 2);
                        p[r] = uni ? 1.0f : ((key < L) ? exp2f(sacc[r]) : 0.0f);
                    }
                }
#pragma unroll
                for (int r = 0; r < 16; r++) rs += p[r];

#pragma unroll
                for (int s2 = 0; s2 < 2; s2++) {
                    int s = t * 2 + s2;
                    H8U pa;
#pragma unroll
                    for (int j = 0; j < 8; j++) pa.h[j] = (_Float16)p[s2 * 8 + j];
                    int cb = (s * 32 + hi * 8) ^ xr;
                    {
                        int off = l31 * 128 + cb;
                        H8U vf;
                        vf.u[0] = *(const uint2v*)(vsmB + off);
                        vf.u[1] = *(const uint2v*)(vsmB + (off ^ 16));
                        oacc0 = __builtin_amdgcn_mfma_f32_32x32x16_f16(pa.h, vf.h, oacc0, 0, 0, 0);
                    }
                    {
                        int off = (32 + l31) * 128 + cb;
                        H8U vf;
                        vf.u[0] = *(const uint2v*)(vsmB + off);
                        vf.u[1] = *(const uint2v*)(vsmB + (off ^ 16));
                        oacc1 = __builtin_amdgcn_mfma_f32_32x32x16_f16(pa.h, vf.h, oacc1, 0, 0, 0);
                    }
                }
            }
        }
        __syncthreads();
    }

    float* ocs = (float*)&ksm[0][0];
    float* rss = (float*)&vtsm[0][0];
    if (ks == 1) {
        int sb = wq * 2048;
        rss[wq * 64 + lane] = rs;
#pragma unroll
        for (int i = 0; i < 16; i++) ocs[sb + i * 64 + lane] = oacc0[i];
#pragma unroll
        for (int i = 0; i < 16; i++) ocs[sb + (16 + i) * 64 + lane] = oacc1[i];
    }
    __syncthreads();
    if (ks == 0) {
        int sb = wq * 2048;
        rs += rss[wq * 64 + lane];
#pragma unroll
        for (int i = 0; i < 16; i++) oacc0[i] += ocs[sb + i * 64 + lane];
#pragma unroll
        for (int i = 0; i < 16; i++) oacc1[i] += ocs[sb + (16 + i) * 64 + lane];

        float rstot = rs + __shfl_xor(rs, 32, 64);
        _Float16* outb = aout + ((size_t)b * 2048 + q0 + wq * 32) * 512 + h * 64;
#pragma unroll
        for (int r = 0; r < 16; r++) {
            int qi = (r & 3) + 8 * (r >> 2) + 4 * hi;
            float inv = 1.0f / __shfl(rstot, qi, 64);
            outb[(size_t)qi * 512 + l31] = (_Float16)(oacc0[r] * inv);
            outb[(size_t)qi * 512 + 32 + l31] = (_Float16)(oacc1[r] * inv);
        }
    }
}

// ---------------- K3abl: phase-ablation clone of attn (outputs to scratch, REP repeats) -------
// MODE 1: staging + barriers + prefetch only.  MODE 3: + QK MFMA + softmax/mask/rowsum (no PV).
// Same grid/waves/LDS/schedule as attn_kernel; keepalives prevent DCE (dummy/rs -> scratch).
template<int MODE, int REP>
__global__ __launch_bounds__(256) void attn_abl_kernel(
        const _Float16* __restrict__ qws, const _Float16* __restrict__ kws,
        const _Float16* __restrict__ vtws, const int* __restrict__ vlens,
        float* __restrict__ scratch) {
    int idx = blockIdx.x;
    int b = ((idx & 3) + (idx >> 8)) & 3;
    int h = (idx >> 2) & 7;
    int q0 = ((idx >> 5) & 31) * 64;
    int bh = b * 8 + h;
    int L = vlens[b];
    bool uni = (L == 0);
    int nkt = uni ? 32 : ((L + 63) >> 6);
    int nfull = uni ? 0 : (L >> 6);

    int tid = threadIdx.x;
    int wid = tid >> 6;
    int ks = wid >> 1;
    int wq = wid & 1;
    int lane = tid & 63;
    int l31 = lane & 31, hi = lane >> 5;

    __shared__ __align__(16) _Float16 ksm[2][64 * 64];
    __shared__ __align__(16) _Float16 vtsm[2][64 * 64];

    const _Float16* kbase = kws + (size_t)bh * 2048 * 64;
    const _Float16* vtbase = vtws + (size_t)bh * 64 * 2048;

    half8 qf[4];
    if (MODE >= 3) {
        const _Float16* qrow = qws + ((size_t)bh * 2048 + q0 + wq * 32 + l31) * 64;
#pragma unroll
        for (int kc = 0; kc < 4; kc++) {
            qf[kc] = *(const half8*)(qrow + kc * 16 + hi * 8);
            qf[kc] = qf[kc] * (_Float16)(0.125f * LOG2E);
        }
    }

    int htid = tid & 127;
    int tt = tid >> 7;
    int seg = htid & 7;
    int trow = htid >> 3;
    int xr = (l31 & 15) << 3;
    char* ksmB = (char*)&ksm[tt][0];
    char* vsmB = (char*)&vtsm[tt][0];

    float dummy = 0.f, rs = 0.f;

    for (int rep = 0; rep < REP; rep++) {
        half8 kreg[4], vreg[4];
        if (tt < nkt) {
            const _Float16* kp = kbase + (size_t)tt * 4096;
            const _Float16* vp = vtbase + tt * 64;
#pragma unroll
            for (int i = 0; i < 4; i++) {
                int row = i * 16 + trow;
                kreg[i] = *(const half8*)(kp + row * 64 + seg * 8);
                vreg[i] = *(const half8*)(vp + (size_t)row * 2048 + seg * 8);
            }
        }

        for (int kt2 = 0; kt2 < nkt; kt2 += 2) {
            if (kt2 + tt < nkt) {
#pragma unroll
                for (int i = 0; i < 4; i++) {
                    int row = i * 16 + trow;
                    int wo = row * 128 + ((seg * 16) ^ ((row & 15) << 3));
                    H8U kv, vv;
                    kv.h = kreg[i]; vv.h = vreg[i];
                    *(uint2v*)(ksmB + wo) = kv.u[0];
                    *(uint2v*)(ksmB + (wo ^ 8)) = kv.u[1];
                    *(uint2v*)(vsmB + wo) = vv.u[0];
                    *(uint2v*)(vsmB + (wo ^ 8)) = vv.u[1];
                }
            }
            __syncthreads();
            int nxt = kt2 + 2 + tt;
            if (nxt < nkt) {
                const _Float16* kp = kbase + (size_t)nxt * 4096;
                const _Float16* vp = vtbase + nxt * 64;
#pragma unroll
                for (int i = 0; i < 4; i++) {
                    int row = i * 16 + trow;
                    kreg[i] = *(const half8*)(kp + row * 64 + seg * 8);
                    vreg[i] = *(const half8*)(vp + (size_t)row * 2048 + seg * 8);
                }
            }

            int kt = kt2 + ks;
            if (MODE >= 3) {
                if (kt < nkt) {
#pragma unroll
                    for (int t = 0; t < 2; t++) {
                        floatx16 sacc;
#pragma unroll
                        for (int i = 0; i < 16; i++) sacc[i] = 0.f;
                        int rbase = (t * 32 + l31) * 128;
#pragma unroll
                        for (int kc = 0; kc < 4; kc++) {
                            int off = rbase + ((kc * 32 + hi * 16) ^ xr);
                            H8U kf;
                            kf.u[0] = *(const uint2v*)(ksmB + off);
                            kf.u[1] = *(const uint2v*)(ksmB + (off ^ 8));
                            sacc = __builtin_amdgcn_mfma_f32_32x32x16_f16(kf.h, qf[kc], sacc, 0, 0, 0);
                        }
                        float p[16];
                        if (kt < nfull) {
#pragma unroll
                            for (int r = 0; r < 16; r++) p[r] = exp2f(sacc[r]);
                        } else {
                            int kb0 = kt * 64 + t * 32 + 4 * hi;
#pragma unroll
                            for (int r = 0; r < 16; r++) {
                                int key = kb0 + (r & 3) + 8 * (r >> 2);
                                p[r] = uni ? 1.0f : ((key < L) ? exp2f(sacc[r]) : 0.0f);
                            }
                        }
#pragma unroll
                        for (int r = 0; r < 16; r++) rs += p[r];
                    }
                }
            } else {
                // keep prefetched regs live without consuming them in LDS this iteration
                dummy += (float)kreg[0][0] + (float)vreg[0][0];
            }
            __syncthreads();
        }
    }

    scratch[(size_t)blockIdx.x * 256 + tid] = dummy + rs;
}

// ---------------- K4: output projection, 64x128 tiles (reg-prefetch dbuf) -> f32 ----------------
__global__ __launch_bounds__(256) void gemm_out_kernel(
        const _Float16* __restrict__ A, const _Float16* __restrict__ BT,
        const float* __restrict__ bias, float* __restrict__ out) {
    __shared__ __align__(16) _Float16 Asm[64][72];
    __shared__ __align__(16) _Float16 Bsm[128][72];

    int tid = threadIdx.x;
    int wave = tid >> 6, lane = tid & 63;
    int lrow = lane & 15, quad = lane >> 4;
    int mBase = blockIdx.x * 64, nBase = blockIdx.y * 128;
    int mrow = wave * 16 + lrow;

    const floatx4 fz = {0.f, 0.f, 0.f, 0.f};
    floatx4 acc[8];
    for (int i = 0; i < 8; i++) acc[i] = fz;

    int arow[2], aseg[2], brow[4], bseg[4];
    for (int i = 0; i < 2; i++) { int f = i * 256 + tid; arow[i] = f >> 3; aseg[i] = f & 7; }
    for (int i = 0; i < 4; i++) { int f = i * 256 + tid; brow[i] = f >> 3; bseg[i] = f & 7; }

    half8 areg[2], breg[4];
    for (int i = 0; i < 2; i++)
        areg[i] = *(const half8*)(A + (size_t)(mBase + arow[i]) * 512 + aseg[i] * 8);
    for (int i = 0; i < 4; i++)
        breg[i] = *(const half8*)(BT + (size_t)(nBase + brow[i]) * 512 + bseg[i] * 8);

    for (int kb = 0; kb < 512; kb += 64) {
        for (int i = 0; i < 2; i++) *(half8*)&Asm[arow[i]][aseg[i] * 8] = areg[i];
        for (int i = 0; i < 4; i++) *(half8*)&Bsm[brow[i]][bseg[i] * 8] = breg[i];
        __syncthreads();
        if (kb + 64 < 512) {
            int kn = kb + 64;
            for (int i = 0; i < 2; i++)
                areg[i] = *(const half8*)(A + (size_t)(mBase + arow[i]) * 512 + kn + aseg[i] * 8);
            for (int i = 0; i < 4; i++)
                breg[i] = *(const half8*)(BT + (size_t)(nBase + brow[i]) * 512 + kn + bseg[i] * 8);
        }
        for (int kc = 0; kc < 2; kc++) {
            int ko_ = kc * 32 + quad * 8;
            half8 a = *(const half8*)&Asm[mrow][ko_];
            for (int nt = 0; nt < 8; nt++) {
                half8 b = *(const half8*)&Bsm[nt * 16 + lrow][ko_];
                acc[nt] = __builtin_amdgcn_mfma_f32_16x16x32_f16(a, b, acc[nt], 0, 0, 0);
            }
        }
        __syncthreads();
    }

    for (int nt = 0; nt < 8; nt++) {
        int gc = nBase + nt * 16 + lrow;
        float bb = bias[gc];
        for (int r = 0; r < 4; r++) {
            int gr = mBase + wave * 16 + quad * 4 + r;
            out[(size_t)gr * 512 + gc] = acc[nt][r] + bb;
        }
    }
}

extern "C" void kernel_launch(void* const* d_in, const int* in_sizes, int n_in,
                              void* d_out, int out_size, void* d_ws, size_t ws_size,
                              hipStream_t stream) {
    const float* Q  = (const float*)d_in[0];
    const float* K  = (const float*)d_in[1];
    const float* V  = (const float*)d_in[2];
    const int*   VL = (const int*)d_in[3];
    const float* Wq = (const float*)d_in[4];
    const float* bq = (const float*)d_in[5];
    const float* Wk = (const float*)d_in[6];
    const float* bk = (const float*)d_in[7];
    const float* Wv = (const float*)d_in[8];
    const float* bv = (const float*)d_in[9];
    const float* Wo = (const float*)d_in[10];
    const float* bo = (const float*)d_in[11];

    char* ws = (char*)d_ws;
    _Float16* WT   = (_Float16*)ws;                                  // 2 MiB
    _Float16* qws  = (_Float16*)(ws + (size_t)(2)  * 1024 * 1024);   // 8 MiB [bh][s][hd]
    _Float16* kws  = (_Float16*)(ws + (size_t)(10) * 1024 * 1024);   // 8 MiB [bh][s][hd]
    _Float16* aout = (_Float16*)(ws + (size_t)(18) * 1024 * 1024);   // 8 MiB [8192,512]
    _Float16* vtws = (_Float16*)(ws + (size_t)(26) * 1024 * 1024);   // 8 MiB [bh][hd][s]
    float*    scr  = (float*)   (ws + (size_t)(34) * 1024 * 1024);   // 1 MiB ablation scratch

    transpose_w_kernel<<<dim3(8, 8, 4), 256, 0, stream>>>(Wq, Wk, Wv, Wo, WT);
    gemm_qkv_kernel<<<dim3(128, 4, 3), 256, 0, stream>>>(Q, K, V, WT, bq, bk, bv, VL, qws, kws, vtws);
    attn_kernel<<<dim3(1024, 1, 1), 256, 0, stream>>>(qws, kws, vtws, VL, aout);
    attn_abl_kernel<1, 8><<<dim3(1024, 1, 1), 256, 0, stream>>>(qws, kws, vtws, VL, scr);
    attn_abl_kernel<3, 2><<<dim3(1024, 1, 1), 256, 0, stream>>>(qws, kws, vtws, VL, scr + 262144);
    gemm_out_kernel<<<dim3(128, 4, 1), 256, 0, stream>>>(aout, WT + (size_t)3 * 512 * 512, bo, (float*)d_out);
}

// Round 10
// 243.555 us; speedup vs baseline: 1.4418x; 1.4418x over previous
//
#include <hip/hip_runtime.h>
#include <hip/hip_bf16.h>

typedef _Float16 half8 __attribute__((ext_vector_type(8)));
typedef _Float16 half4 __attribute__((ext_vector_type(4)));
typedef _Float16 half2t __attribute__((ext_vector_type(2)));
typedef float floatx4 __attribute__((ext_vector_type(4)));
typedef float floatx16 __attribute__((ext_vector_type(16)));
typedef unsigned int uint2v __attribute__((ext_vector_type(2)));

#define LOG2E 1.44269504088896340736f

__device__ __forceinline__ half8 cvt8r(floatx4 a, floatx4 b) {
    half8 h;
    h[0] = (_Float16)a[0]; h[1] = (_Float16)a[1]; h[2] = (_Float16)a[2]; h[3] = (_Float16)a[3];
    h[4] = (_Float16)b[0]; h[5] = (_Float16)b[1]; h[6] = (_Float16)b[2]; h[7] = (_Float16)b[3];
    return h;
}

union H8U { half8 h; half2t v2[4]; uint2v u[2]; };

__device__ __forceinline__ half2t pk16(float a, float b) {
    return __builtin_bit_cast(half2t, __builtin_amdgcn_cvt_pkrtz(a, b));
}

// ---------------- K1: transpose + convert W (f32 [512x512]) -> WT fp16 [n][k] ----------------
__global__ __launch_bounds__(256) void transpose_w_kernel(
        const float* __restrict__ Wq, const float* __restrict__ Wk,
        const float* __restrict__ Wv, const float* __restrict__ Wo,
        _Float16* __restrict__ out) {
    const float* W = (blockIdx.z == 0) ? Wq : (blockIdx.z == 1) ? Wk : (blockIdx.z == 2) ? Wv : Wo;
    _Float16* o = out + (size_t)blockIdx.z * 512 * 512;
    __shared__ __align__(16) _Float16 t[64][72];
    int r0 = blockIdx.x * 64, c0 = blockIdx.y * 64;
    int tid = threadIdx.x;
    for (int i = 0; i < 2; i++) {
        int f = i * 256 + tid;
        int row = f >> 3, seg = f & 7;
        const float* p = W + (size_t)(r0 + row) * 512 + c0 + seg * 8;
        *(half8*)&t[row][seg * 8] = cvt8r(*(const floatx4*)p, *(const floatx4*)(p + 4));
    }
    __syncthreads();
    for (int i = 0; i < 2; i++) {
        int f = i * 256 + tid;
        int crow = f >> 3, seg = f & 7;
        half8 hv;
        for (int j = 0; j < 8; j++) hv[j] = t[seg * 8 + j][crow];
        *(half8*)(o + (size_t)(c0 + crow) * 512 + r0 + seg * 8) = hv;
    }
}

// ---------------- K2: QKV projection GEMM, 64x128 tiles; dead K/V blocks skipped ----------------
__global__ __launch_bounds__(256) void gemm_qkv_kernel(
        const float* __restrict__ Xq, const float* __restrict__ Xk, const float* __restrict__ Xv,
        const _Float16* __restrict__ WTall,
        const float* __restrict__ bq, const float* __restrict__ bk, const float* __restrict__ bv,
        const int* __restrict__ vlens,
        _Float16* __restrict__ qo, _Float16* __restrict__ ko2, _Float16* __restrict__ vto) {
    int z = blockIdx.z;
    int mBase = blockIdx.x * 64, nBase = blockIdx.y * 128;

    if (z >= 1) {
        int b_ = mBase >> 11, s0 = mBase & 2047;
        int L = vlens[b_];
        if (s0 >= L && !(z == 2 && L == 0)) return;
    }

    const float* X = (z == 0) ? Xq : (z == 1) ? Xk : Xv;
    const _Float16* BT = WTall + (size_t)z * 512 * 512;
    const float* bias = (z == 0) ? bq : (z == 1) ? bk : bv;

    __shared__ __align__(16) _Float16 Asm[64][72];
    __shared__ __align__(16) _Float16 Bsm[128][72];

    int tid = threadIdx.x;
    int wave = tid >> 6, lane = tid & 63;
    int lrow = lane & 15, quad = lane >> 4;
    int mrow = wave * 16 + lrow;

    const floatx4 fz = {0.f, 0.f, 0.f, 0.f};
    floatx4 acc[8];
    for (int i = 0; i < 8; i++) acc[i] = fz;

    int arow[2], aseg[2], brow[4], bseg[4];
    for (int i = 0; i < 2; i++) { int f = i * 256 + tid; arow[i] = f >> 3; aseg[i] = f & 7; }
    for (int i = 0; i < 4; i++) { int f = i * 256 + tid; brow[i] = f >> 3; bseg[i] = f & 7; }

    floatx4 areg[2][2];
    half8 breg[4];
    for (int i = 0; i < 2; i++) {
        const float* pa = X + (size_t)(mBase + arow[i]) * 512 + aseg[i] * 8;
        areg[i][0] = *(const floatx4*)pa;
        areg[i][1] = *(const floatx4*)(pa + 4);
    }
    for (int i = 0; i < 4; i++)
        breg[i] = *(const half8*)(BT + (size_t)(nBase + brow[i]) * 512 + bseg[i] * 8);

    for (int kb = 0; kb < 512; kb += 64) {
        for (int i = 0; i < 2; i++) *(half8*)&Asm[arow[i]][aseg[i] * 8] = cvt8r(areg[i][0], areg[i][1]);
        for (int i = 0; i < 4; i++) *(half8*)&Bsm[brow[i]][bseg[i] * 8] = breg[i];
        __syncthreads();
        if (kb + 64 < 512) {
            int kn = kb + 64;
            for (int i = 0; i < 2; i++) {
                const float* pa = X + (size_t)(mBase + arow[i]) * 512 + kn + aseg[i] * 8;
                areg[i][0] = *(const floatx4*)pa;
                areg[i][1] = *(const floatx4*)(pa + 4);
            }
            for (int i = 0; i < 4; i++)
                breg[i] = *(const half8*)(BT + (size_t)(nBase + brow[i]) * 512 + kn + bseg[i] * 8);
        }
        for (int kc = 0; kc < 2; kc++) {
            int ko_ = kc * 32 + quad * 8;
            half8 a = *(const half8*)&Asm[mrow][ko_];
            for (int nt = 0; nt < 8; nt++) {
                half8 b = *(const half8*)&Bsm[nt * 16 + lrow][ko_];
                acc[nt] = __builtin_amdgcn_mfma_f32_16x16x32_f16(a, b, acc[nt], 0, 0, 0);
            }
        }
        __syncthreads();
    }

    if (z == 2) {
        for (int nt = 0; nt < 8; nt++) {
            int gc = nBase + nt * 16 + lrow;
            float bb = bias[gc];
            int h = gc >> 6, hd = gc & 63;
            int gr = mBase + wave * 16 + quad * 4;
            int b_ = gr >> 11, s = gr & 2047;
            half4 hv;
            for (int r = 0; r < 4; r++) hv[r] = (_Float16)(acc[nt][r] + bb);
            *(half4*)(vto + (((size_t)(b_ * 8 + h) * 64 + hd) * 2048 + s)) = hv;
        }
    } else {
        _Float16* out = (z == 0) ? qo : ko2;
        for (int nt = 0; nt < 8; nt++) {
            int gc = nBase + nt * 16 + lrow;
            float bb = bias[gc];
            int h = gc >> 6, hd = gc & 63;
            for (int r = 0; r < 4; r++) {
                int gr = mBase + wave * 16 + quad * 4 + r;
                int b_ = gr >> 11, s = gr & 2047;
                out[(((size_t)b_ * 8 + h) * 2048 + s) * 64 + hd] = (_Float16)(acc[nt][r] + bb);
            }
        }
    }
}

// ---------------- K3: flash attention v18: r7 structure + PV VALU diet ----------------
// Ablation (r9): staging 12.6 / QK+SM 16.4 / PV 29.0 µs of 58. PV's excess = pack VALU
// (32 scalar cvt + packs). Fix: v_cvt_pkrtz (48->16 VALU/tile), tree rowsum, raw v_exp_f32.
__global__ __launch_bounds__(256) void attn_kernel(
        const _Float16* __restrict__ qws, const _Float16* __restrict__ kws,
        const _Float16* __restrict__ vtws, const int* __restrict__ vlens,
        _Float16* __restrict__ aout) {
    int idx = blockIdx.x;
    int b = ((idx & 3) + (idx >> 8)) & 3;
    int h = (idx >> 2) & 7;
    int q0 = ((idx >> 5) & 31) * 64;
    int bh = b * 8 + h;
    int L = vlens[b];
    bool uni = (L == 0);
    int nkt = uni ? 32 : ((L + 63) >> 6);
    int nfull = uni ? 0 : (L >> 6);

    int tid = threadIdx.x;
    int wid = tid >> 6;
    int wq = wid & 1, ks = wid >> 1;
    int lane = tid & 63;
    int l31 = lane & 31, hi = lane >> 5;

    __shared__ __align__(16) _Float16 ksm[2][64 * 64];
    __shared__ __align__(16) _Float16 vtsm[2][64 * 64];

    const _Float16* kbase = kws + (size_t)bh * 2048 * 64;
    const _Float16* vtbase = vtws + (size_t)bh * 64 * 2048;

    half8 qf[4];
    {
        const _Float16* qrow = qws + ((size_t)bh * 2048 + q0 + wq * 32 + l31) * 64;
#pragma unroll
        for (int kc = 0; kc < 4; kc++) {
            qf[kc] = *(const half8*)(qrow + kc * 16 + hi * 8);
            qf[kc] = qf[kc] * (_Float16)(0.125f * LOG2E);
        }
    }

    floatx16 oacc0, oacc1;
#pragma unroll
    for (int i = 0; i < 16; i++) { oacc0[i] = 0.f; oacc1[i] = 0.f; }
    float rs = 0.f;

    int htid = tid & 127;
    int tt = tid >> 7;
    int seg = htid & 7;
    int trow = htid >> 3;
    int xr = (l31 & 15) << 3;
    char* ksmB = (char*)&ksm[tt][0];
    char* vsmB = (char*)&vtsm[tt][0];

    half8 kreg[4], vreg[4];
    if (tt < nkt) {
        const _Float16* kp = kbase + (size_t)tt * 4096;
        const _Float16* vp = vtbase + tt * 64;
#pragma unroll
        for (int i = 0; i < 4; i++) {
            int row = i * 16 + trow;
            kreg[i] = *(const half8*)(kp + row * 64 + seg * 8);
            vreg[i] = *(const half8*)(vp + (size_t)row * 2048 + seg * 8);
        }
    }

    for (int kt2 = 0; kt2 < nkt; kt2 += 2) {
        if (kt2 + tt < nkt) {
#pragma unroll
            for (int i = 0; i < 4; i++) {
                int row = i * 16 + trow;
                int wo = row * 128 + ((seg * 16) ^ ((row & 15) << 3));
                H8U kv, vv;
                kv.h = kreg[i]; vv.h = vreg[i];
                *(uint2v*)(ksmB + wo) = kv.u[0];
                *(uint2v*)(ksmB + (wo ^ 8)) = kv.u[1];
                *(uint2v*)(vsmB + wo) = vv.u[0];
                *(uint2v*)(vsmB + (wo ^ 8)) = vv.u[1];
            }
        }
        __syncthreads();
        int nxt = kt2 + 2 + tt;
        if (nxt < nkt) {
            const _Float16* kp = kbase + (size_t)nxt * 4096;
            const _Float16* vp = vtbase + nxt * 64;
#pragma unroll
            for (int i = 0; i < 4; i++) {
                int row = i * 16 + trow;
                kreg[i] = *(const half8*)(kp + row * 64 + seg * 8);
                vreg[i] = *(const half8*)(vp + (size_t)row * 2048 + seg * 8);
            }
        }

        int kt = kt2 + ks;
        if (kt < nkt) {
#pragma unroll
            for (int t = 0; t < 2; t++) {
                floatx16 sacc;
#pragma unroll
                for (int i = 0; i < 16; i++) sacc[i] = 0.f;
                int rbase = (t * 32 + l31) * 128;
#pragma unroll
                for (int kc = 0; kc < 4; kc++) {
                    int off = rbase + ((kc * 32 + hi * 16) ^ xr);
                    H8U kf;
                    kf.u[0] = *(const uint2v*)(ksmB + off);
                    kf.u[1] = *(const uint2v*)(ksmB + (off ^ 8));
                    sacc = __builtin_amdgcn_mfma_f32_32x32x16_f16(kf.h, qf[kc], sacc, 0, 0, 0);
                }

                float p[16];
                if (kt < nfull) {
#pragma unroll
                    for (int r = 0; r < 16; r++) p[r] = __builtin_amdgcn_exp2f(sacc[r]);
                } else {
                    int kb0 = kt * 64 + t * 32 + 4 * hi;
#pragma unroll
                    for (int r = 0; r < 16; r++) {
                        int key = kb0 + (r & 3) + 8 * (r >> 2);
                        p[r] = uni ? 1.0f : ((key < L) ? __builtin_amdgcn_exp2f(sacc[r]) : 0.0f);
                    }
                }
                rs += (((p[0] + p[1]) + (p[2] + p[3])) + ((p[4] + p[5]) + (p[6] + p[7])))
                    + (((p[8] + p[9]) + (p[10] + p[11])) + ((p[12] + p[13]) + (p[14] + p[15])));

#pragma unroll
                for (int s2 = 0; s2 < 2; s2++) {
                    int s = t * 2 + s2;
                    H8U pa;
#pragma unroll
                    for (int jj = 0; jj < 4; jj++)
                        pa.v2[jj] = pk16(p[s2 * 8 + jj * 2], p[s2 * 8 + jj * 2 + 1]);
                    int cb = (s * 32 + hi * 8) ^ xr;
                    {
                        int off = l31 * 128 + cb;
                        H8U vf;
                        vf.u[0] = *(const uint2v*)(vsmB + off);
                        vf.u[1] = *(const uint2v*)(vsmB + (off ^ 16));
                        oacc0 = __builtin_amdgcn_mfma_f32_32x32x16_f16(pa.h, vf.h, oacc0, 0, 0, 0);
                    }
                    {
                        int off = (32 + l31) * 128 + cb;
                        H8U vf;
                        vf.u[0] = *(const uint2v*)(vsmB + off);
                        vf.u[1] = *(const uint2v*)(vsmB + (off ^ 16));
                        oacc1 = __builtin_amdgcn_mfma_f32_32x32x16_f16(pa.h, vf.h, oacc1, 0, 0, 0);
                    }
                }
            }
        }
        __syncthreads();
    }

    float* ocs = (float*)&ksm[0][0];
    float* rss = (float*)&vtsm[0][0];
    if (ks == 1) {
        int sb = wq * 2048;
        rss[wq * 64 + lane] = rs;
#pragma unroll
        for (int i = 0; i < 16; i++) ocs[sb + i * 64 + lane] = oacc0[i];
#pragma unroll
        for (int i = 0; i < 16; i++) ocs[sb + (16 + i) * 64 + lane] = oacc1[i];
    }
    __syncthreads();
    if (ks == 0) {
        int sb = wq * 2048;
        rs += rss[wq * 64 + lane];
#pragma unroll
        for (int i = 0; i < 16; i++) oacc0[i] += ocs[sb + i * 64 + lane];
#pragma unroll
        for (int i = 0; i < 16; i++) oacc1[i] += ocs[sb + (16 + i) * 64 + lane];

        float rstot = rs + __shfl_xor(rs, 32, 64);
        _Float16* outb = aout + ((size_t)b * 2048 + q0 + wq * 32) * 512 + h * 64;
#pragma unroll
        for (int r = 0; r < 16; r++) {
            int qi = (r & 3) + 8 * (r >> 2) + 4 * hi;
            float inv = 1.0f / __shfl(rstot, qi, 64);
            outb[(size_t)qi * 512 + l31] = (_Float16)(oacc0[r] * inv);
            outb[(size_t)qi * 512 + 32 + l31] = (_Float16)(oacc1[r] * inv);
        }
    }
}

// ---------------- K4: output projection, 64x128 tiles (reg-prefetch dbuf) -> f32 ----------------
__global__ __launch_bounds__(256) void gemm_out_kernel(
        const _Float16* __restrict__ A, const _Float16* __restrict__ BT,
        const float* __restrict__ bias, float* __restrict__ out) {
    __shared__ __align__(16) _Float16 Asm[64][72];
    __shared__ __align__(16) _Float16 Bsm[128][72];

    int tid = threadIdx.x;
    int wave = tid >> 6, lane = tid & 63;
    int lrow = lane & 15, quad = lane >> 4;
    int mBase = blockIdx.x * 64, nBase = blockIdx.y * 128;
    int mrow = wave * 16 + lrow;

    const floatx4 fz = {0.f, 0.f, 0.f, 0.f};
    floatx4 acc[8];
    for (int i = 0; i < 8; i++) acc[i] = fz;

    int arow[2], aseg[2], brow[4], bseg[4];
    for (int i = 0; i < 2; i++) { int f = i * 256 + tid; arow[i] = f >> 3; aseg[i] = f & 7; }
    for (int i = 0; i < 4; i++) { int f = i * 256 + tid; brow[i] = f >> 3; bseg[i] = f & 7; }

    half8 areg[2], breg[4];
    for (int i = 0; i < 2; i++)
        areg[i] = *(const half8*)(A + (size_t)(mBase + arow[i]) * 512 + aseg[i] * 8);
    for (int i = 0; i < 4; i++)
        breg[i] = *(const half8*)(BT + (size_t)(nBase + brow[i]) * 512 + bseg[i] * 8);

    for (int kb = 0; kb < 512; kb += 64) {
        for (int i = 0; i < 2; i++) *(half8*)&Asm[arow[i]][aseg[i] * 8] = areg[i];
        for (int i = 0; i < 4; i++) *(half8*)&Bsm[brow[i]][bseg[i] * 8] = breg[i];
        __syncthreads();
        if (kb + 64 < 512) {
            int kn = kb + 64;
            for (int i = 0; i < 2; i++)
                areg[i] = *(const half8*)(A + (size_t)(mBase + arow[i]) * 512 + kn + aseg[i] * 8);
            for (int i = 0; i < 4; i++)
                breg[i] = *(const half8*)(BT + (size_t)(nBase + brow[i]) * 512 + kn + bseg[i] * 8);
        }
        for (int kc = 0; kc < 2; kc++) {
            int ko_ = kc * 32 + quad * 8;
            half8 a = *(const half8*)&Asm[mrow][ko_];
            for (int nt = 0; nt < 8; nt++) {
                half8 b = *(const half8*)&Bsm[nt * 16 + lrow][ko_];
                acc[nt] = __builtin_amdgcn_mfma_f32_16x16x32_f16(a, b, acc[nt], 0, 0, 0);
            }
        }
        __syncthreads();
    }

    for (int nt = 0; nt < 8; nt++) {
        int gc = nBase + nt * 16 + lrow;
        float bb = bias[gc];
        for (int r = 0; r < 4; r++) {
            int gr = mBase + wave * 16 + quad * 4 + r;
            out[(size_t)gr * 512 + gc] = acc[nt][r] + bb;
        }
    }
}

extern "C" void kernel_launch(void* const* d_in, const int* in_sizes, int n_in,
                              void* d_out, int out_size, void* d_ws, size_t ws_size,
                              hipStream_t stream) {
    const float* Q  = (const float*)d_in[0];
    const float* K  = (const float*)d_in[1];
    const float* V  = (const float*)d_in[2];
    const int*   VL = (const int*)d_in[3];
    const float* Wq = (const float*)d_in[4];
    const float* bq = (const float*)d_in[5];
    const float* Wk = (const float*)d_in[6];
    const float* bk = (const float*)d_in[7];
    const float* Wv = (const float*)d_in[8];
    const float* bv = (const float*)d_in[9];
    const float* Wo = (const float*)d_in[10];
    const float* bo = (const float*)d_in[11];

    char* ws = (char*)d_ws;
    _Float16* WT   = (_Float16*)ws;                                  // 2 MiB
    _Float16* qws  = (_Float16*)(ws + (size_t)(2)  * 1024 * 1024);   // 8 MiB [bh][s][hd]
    _Float16* kws  = (_Float16*)(ws + (size_t)(10) * 1024 * 1024);   // 8 MiB [bh][s][hd]
    _Float16* aout = (_Float16*)(ws + (size_t)(18) * 1024 * 1024);   // 8 MiB [8192,512]
    _Float16* vtws = (_Float16*)(ws + (size_t)(26) * 1024 * 1024);   // 8 MiB [bh][hd][s]

    transpose_w_kernel<<<dim3(8, 8, 4), 256, 0, stream>>>(Wq, Wk, Wv, Wo, WT);
    // K2 launched 3x (idempotent) — instrumentation to expose its per-dispatch cost in rocprof.
    gemm_qkv_kernel<<<dim3(128, 4, 3), 256, 0, stream>>>(Q, K, V, WT, bq, bk, bv, VL, qws, kws, vtws);
    gemm_qkv_kernel<<<dim3(128, 4, 3), 256, 0, stream>>>(Q, K, V, WT, bq, bk, bv, VL, qws, kws, vtws);
    gemm_qkv_kernel<<<dim3(128, 4, 3), 256, 0, stream>>>(Q, K, V, WT, bq, bk, bv, VL, qws, kws, vtws);
    attn_kernel<<<dim3(1024, 1, 1), 256, 0, stream>>>(qws, kws, vtws, VL, aout);
    gemm_out_kernel<<<dim3(128, 4, 1), 256, 0, stream>>>(aout, WT + (size_t)3 * 512 * 512, bo, (float*)d_out);
}

// Round 12
// 199.980 us; speedup vs baseline: 1.7560x; 1.2179x over previous
//
#include <hip/hip_runtime.h>
#include <hip/hip_bf16.h>

typedef _Float16 half8 __attribute__((ext_vector_type(8)));
typedef _Float16 half4 __attribute__((ext_vector_type(4)));
typedef _Float16 half2t __attribute__((ext_vector_type(2)));
typedef float floatx4 __attribute__((ext_vector_type(4)));
typedef float floatx16 __attribute__((ext_vector_type(16)));
typedef unsigned int uint2v __attribute__((ext_vector_type(2)));

#define LOG2E 1.44269504088896340736f

__device__ __forceinline__ half8 cvt8r(floatx4 a, floatx4 b) {
    half8 h;
    h[0] = (_Float16)a[0]; h[1] = (_Float16)a[1]; h[2] = (_Float16)a[2]; h[3] = (_Float16)a[3];
    h[4] = (_Float16)b[0]; h[5] = (_Float16)b[1]; h[6] = (_Float16)b[2]; h[7] = (_Float16)b[3];
    return h;
}

union H8U { half8 h; half2t v2[4]; uint2v u[2]; };

__device__ __forceinline__ half2t pk16(float a, float b) {
    return __builtin_bit_cast(half2t, __builtin_amdgcn_cvt_pkrtz(a, b));
}

// ---------------- K1: transpose + convert W (f32 [512x512]) -> WT fp16 [n][k] ----------------
__global__ __launch_bounds__(256) void transpose_w_kernel(
        const float* __restrict__ Wq, const float* __restrict__ Wk,
        const float* __restrict__ Wv, const float* __restrict__ Wo,
        _Float16* __restrict__ out) {
    const float* W = (blockIdx.z == 0) ? Wq : (blockIdx.z == 1) ? Wk : (blockIdx.z == 2) ? Wv : Wo;
    _Float16* o = out + (size_t)blockIdx.z * 512 * 512;
    __shared__ __align__(16) _Float16 t[64][72];
    int r0 = blockIdx.x * 64, c0 = blockIdx.y * 64;
    int tid = threadIdx.x;
    for (int i = 0; i < 2; i++) {
        int f = i * 256 + tid;
        int row = f >> 3, seg = f & 7;
        const float* p = W + (size_t)(r0 + row) * 512 + c0 + seg * 8;
        *(half8*)&t[row][seg * 8] = cvt8r(*(const floatx4*)p, *(const floatx4*)(p + 4));
    }
    __syncthreads();
    for (int i = 0; i < 2; i++) {
        int f = i * 256 + tid;
        int crow = f >> 3, seg = f & 7;
        half8 hv;
        for (int j = 0; j < 8; j++) hv[j] = t[seg * 8 + j][crow];
        *(half8*)(o + (size_t)(c0 + crow) * 512 + r0 + seg * 8) = hv;
    }
}

// ---------------- K2: QKV projection GEMM, 64x128 tiles; dead K/V blocks skipped ----------------
__global__ __launch_bounds__(256) void gemm_qkv_kernel(
        const float* __restrict__ Xq, const float* __restrict__ Xk, const float* __restrict__ Xv,
        const _Float16* __restrict__ WTall,
        const float* __restrict__ bq, const float* __restrict__ bk, const float* __restrict__ bv,
        const int* __restrict__ vlens,
        _Float16* __restrict__ qo, _Float16* __restrict__ ko2, _Float16* __restrict__ vto) {
    int z = blockIdx.z;
    int mBase = blockIdx.x * 64, nBase = blockIdx.y * 128;

    if (z >= 1) {
        int b_ = mBase >> 11, s0 = mBase & 2047;
        int L = vlens[b_];
        if (s0 >= L && !(z == 2 && L == 0)) return;
    }

    const float* X = (z == 0) ? Xq : (z == 1) ? Xk : Xv;
    const _Float16* BT = WTall + (size_t)z * 512 * 512;
    const float* bias = (z == 0) ? bq : (z == 1) ? bk : bv;

    __shared__ __align__(16) _Float16 Asm[64][72];
    __shared__ __align__(16) _Float16 Bsm[128][72];

    int tid = threadIdx.x;
    int wave = tid >> 6, lane = tid & 63;
    int lrow = lane & 15, quad = lane >> 4;
    int mrow = wave * 16 + lrow;

    const floatx4 fz = {0.f, 0.f, 0.f, 0.f};
    floatx4 acc[8];
    for (int i = 0; i < 8; i++) acc[i] = fz;

    int arow[2], aseg[2], brow[4], bseg[4];
    for (int i = 0; i < 2; i++) { int f = i * 256 + tid; arow[i] = f >> 3; aseg[i] = f & 7; }
    for (int i = 0; i < 4; i++) { int f = i * 256 + tid; brow[i] = f >> 3; bseg[i] = f & 7; }

    floatx4 areg[2][2];
    half8 breg[4];
    for (int i = 0; i < 2; i++) {
        const float* pa = X + (size_t)(mBase + arow[i]) * 512 + aseg[i] * 8;
        areg[i][0] = *(const floatx4*)pa;
        areg[i][1] = *(const floatx4*)(pa + 4);
    }
    for (int i = 0; i < 4; i++)
        breg[i] = *(const half8*)(BT + (size_t)(nBase + brow[i]) * 512 + bseg[i] * 8);

    for (int kb = 0; kb < 512; kb += 64) {
        for (int i = 0; i < 2; i++) *(half8*)&Asm[arow[i]][aseg[i] * 8] = cvt8r(areg[i][0], areg[i][1]);
        for (int i = 0; i < 4; i++) *(half8*)&Bsm[brow[i]][bseg[i] * 8] = breg[i];
        __syncthreads();
        if (kb + 64 < 512) {
            int kn = kb + 64;
            for (int i = 0; i < 2; i++) {
                const float* pa = X + (size_t)(mBase + arow[i]) * 512 + kn + aseg[i] * 8;
                areg[i][0] = *(const floatx4*)pa;
                areg[i][1] = *(const floatx4*)(pa + 4);
            }
            for (int i = 0; i < 4; i++)
                breg[i] = *(const half8*)(BT + (size_t)(nBase + brow[i]) * 512 + kn + bseg[i] * 8);
        }
        for (int kc = 0; kc < 2; kc++) {
            int ko_ = kc * 32 + quad * 8;
            half8 a = *(const half8*)&Asm[mrow][ko_];
            for (int nt = 0; nt < 8; nt++) {
                half8 b = *(const half8*)&Bsm[nt * 16 + lrow][ko_];
                acc[nt] = __builtin_amdgcn_mfma_f32_16x16x32_f16(a, b, acc[nt], 0, 0, 0);
            }
        }
        __syncthreads();
    }

    if (z == 2) {
        for (int nt = 0; nt < 8; nt++) {
            int gc = nBase + nt * 16 + lrow;
            float bb = bias[gc];
            int h = gc >> 6, hd = gc & 63;
            int gr = mBase + wave * 16 + quad * 4;
            int b_ = gr >> 11, s = gr & 2047;
            half4 hv;
            for (int r = 0; r < 4; r++) hv[r] = (_Float16)(acc[nt][r] + bb);
            *(half4*)(vto + (((size_t)(b_ * 8 + h) * 64 + hd) * 2048 + s)) = hv;
        }
    } else {
        _Float16* out = (z == 0) ? qo : ko2;
        for (int nt = 0; nt < 8; nt++) {
            int gc = nBase + nt * 16 + lrow;
            float bb = bias[gc];
            int h = gc >> 6, hd = gc & 63;
            for (int r = 0; r < 4; r++) {
                int gr = mBase + wave * 16 + quad * 4 + r;
                int b_ = gr >> 11, s = gr & 2047;
                out[(((size_t)b_ * 8 + h) * 2048 + s) * 64 + hd] = (_Float16)(acc[nt][r] + bb);
            }
        }
    }
}

// ---------------- K3: flash attention v19: cost-balanced batch pairing ----------------
// Per-CU work was already uniform in total but imbalanced per block (1 block/batch -> tail at
// E[max] of 4 random costs). Now: sort batches by cost, pair {max,min} and {mid,mid}; block =
// (h, q0, pair) runs the verified 4-wave body once per batch in its pair. Grid 512 -> 2 near-
// equal blocks/CU, ~8 waves/CU sustained to common finish. No extra traffic, no atomics.
__global__ __launch_bounds__(256) void attn_kernel(
        const _Float16* __restrict__ qws, const _Float16* __restrict__ kws,
        const _Float16* __restrict__ vtws, const int* __restrict__ vlens,
        _Float16* __restrict__ aout) {
    int idx = blockIdx.x;
    int pair = (idx >> 8) & 1;
    int r_ = idx & 255;
    int h = r_ & 7;                       // per-XCD head locality under round-robin dispatch
    int q0 = ((r_ >> 3) & 31) * 64;

    // sort batches desc by tile cost (deterministic; identical in all blocks)
    int Lb[4], cost[4];
#pragma unroll
    for (int i = 0; i < 4; i++) {
        Lb[i] = vlens[i];
        cost[i] = (Lb[i] == 0) ? 32 : ((Lb[i] + 63) >> 6);
    }
    int ord[4] = {0, 1, 2, 3};
#pragma unroll
    for (int i = 0; i < 3; i++)
#pragma unroll
        for (int j = 0; j < 3; j++)
            if (cost[ord[j]] < cost[ord[j + 1]]) { int t_ = ord[j]; ord[j] = ord[j + 1]; ord[j + 1] = t_; }

    int tid = threadIdx.x;
    int wid = tid >> 6;
    int wq = wid & 1, ks = wid >> 1;
    int lane = tid & 63;
    int l31 = lane & 31, hi = lane >> 5;

    __shared__ __align__(16) _Float16 ksm[2][64 * 64];
    __shared__ __align__(16) _Float16 vtsm[2][64 * 64];

    int htid = tid & 127;
    int tt = tid >> 7;
    int seg = htid & 7;
    int trow = htid >> 3;
    int xr = (l31 & 15) << 3;
    char* ksmB = (char*)&ksm[tt][0];
    char* vsmB = (char*)&vtsm[tt][0];

    for (int half = 0; half < 2; half++) {
        // pair 0 -> {ord0 (max), ord3 (min)}; pair 1 -> {ord1, ord2}
        int b = (pair == 0) ? (half == 0 ? ord[0] : ord[3]) : (half == 0 ? ord[1] : ord[2]);
        int bh = b * 8 + h;
        int L = Lb[b];
        bool uni = (L == 0);
        int nkt = uni ? 32 : ((L + 63) >> 6);
        int nfull = uni ? 0 : (L >> 6);

        const _Float16* kbase = kws + (size_t)bh * 2048 * 64;
        const _Float16* vtbase = vtws + (size_t)bh * 64 * 2048;

        half8 qf[4];
        {
            const _Float16* qrow = qws + ((size_t)bh * 2048 + q0 + wq * 32 + l31) * 64;
#pragma unroll
            for (int kc = 0; kc < 4; kc++) {
                qf[kc] = *(const half8*)(qrow + kc * 16 + hi * 8);
                qf[kc] = qf[kc] * (_Float16)(0.125f * LOG2E);
            }
        }

        floatx16 oacc0, oacc1;
#pragma unroll
        for (int i = 0; i < 16; i++) { oacc0[i] = 0.f; oacc1[i] = 0.f; }
        float rs = 0.f;

        half8 kreg[4], vreg[4];
        if (tt < nkt) {
            const _Float16* kp = kbase + (size_t)tt * 4096;
            const _Float16* vp = vtbase + tt * 64;
#pragma unroll
            for (int i = 0; i < 4; i++) {
                int row = i * 16 + trow;
                kreg[i] = *(const half8*)(kp + row * 64 + seg * 8);
                vreg[i] = *(const half8*)(vp + (size_t)row * 2048 + seg * 8);
            }
        }

        for (int kt2 = 0; kt2 < nkt; kt2 += 2) {
            if (kt2 + tt < nkt) {
#pragma unroll
                for (int i = 0; i < 4; i++) {
                    int row = i * 16 + trow;
                    int wo = row * 128 + ((seg * 16) ^ ((row & 15) << 3));
                    H8U kv, vv;
                    kv.h = kreg[i]; vv.h = vreg[i];
                    *(uint2v*)(ksmB + wo) = kv.u[0];
                    *(uint2v*)(ksmB + (wo ^ 8)) = kv.u[1];
                    *(uint2v*)(vsmB + wo) = vv.u[0];
                    *(uint2v*)(vsmB + (wo ^ 8)) = vv.u[1];
                }
            }
            __syncthreads();
            int nxt = kt2 + 2 + tt;
            if (nxt < nkt) {
                const _Float16* kp = kbase + (size_t)nxt * 4096;
                const _Float16* vp = vtbase + nxt * 64;
#pragma unroll
                for (int i = 0; i < 4; i++) {
                    int row = i * 16 + trow;
                    kreg[i] = *(const half8*)(kp + row * 64 + seg * 8);
                    vreg[i] = *(const half8*)(vp + (size_t)row * 2048 + seg * 8);
                }
            }

            int kt = kt2 + ks;
            if (kt < nkt) {
#pragma unroll
                for (int t = 0; t < 2; t++) {
                    floatx16 sacc;
#pragma unroll
                    for (int i = 0; i < 16; i++) sacc[i] = 0.f;
                    int rbase = (t * 32 + l31) * 128;
#pragma unroll
                    for (int kc = 0; kc < 4; kc++) {
                        int off = rbase + ((kc * 32 + hi * 16) ^ xr);
                        H8U kf;
                        kf.u[0] = *(const uint2v*)(ksmB + off);
                        kf.u[1] = *(const uint2v*)(ksmB + (off ^ 8));
                        sacc = __builtin_amdgcn_mfma_f32_32x32x16_f16(kf.h, qf[kc], sacc, 0, 0, 0);
                    }

                    float p[16];
                    if (kt < nfull) {
#pragma unroll
                        for (int r = 0; r < 16; r++) p[r] = __builtin_amdgcn_exp2f(sacc[r]);
                    } else {
                        int kb0 = kt * 64 + t * 32 + 4 * hi;
#pragma unroll
                        for (int r = 0; r < 16; r++) {
                            int key = kb0 + (r & 3) + 8 * (r >> 2);
                            p[r] = uni ? 1.0f : ((key < L) ? __builtin_amdgcn_exp2f(sacc[r]) : 0.0f);
                        }
                    }
                    rs += (((p[0] + p[1]) + (p[2] + p[3])) + ((p[4] + p[5]) + (p[6] + p[7])))
                        + (((p[8] + p[9]) + (p[10] + p[11])) + ((p[12] + p[13]) + (p[14] + p[15])));

#pragma unroll
                    for (int s2 = 0; s2 < 2; s2++) {
                        int s = t * 2 + s2;
                        H8U pa;
#pragma unroll
                        for (int jj = 0; jj < 4; jj++)
                            pa.v2[jj] = pk16(p[s2 * 8 + jj * 2], p[s2 * 8 + jj * 2 + 1]);
                        int cb = (s * 32 + hi * 8) ^ xr;
                        {
                            int off = l31 * 128 + cb;
                            H8U vf;
                            vf.u[0] = *(const uint2v*)(vsmB + off);
                            vf.u[1] = *(const uint2v*)(vsmB + (off ^ 16));
                            oacc0 = __builtin_amdgcn_mfma_f32_32x32x16_f16(pa.h, vf.h, oacc0, 0, 0, 0);
                        }
                        {
                            int off = (32 + l31) * 128 + cb;
                            H8U vf;
                            vf.u[0] = *(const uint2v*)(vsmB + off);
                            vf.u[1] = *(const uint2v*)(vsmB + (off ^ 16));
                            oacc1 = __builtin_amdgcn_mfma_f32_32x32x16_f16(pa.h, vf.h, oacc1, 0, 0, 0);
                        }
                    }
                }
            }
            __syncthreads();
        }

        // combine key-split partials: ks=1 -> LDS -> ks=0 adds, normalizes, stores
        float* ocs = (float*)&ksm[0][0];
        float* rss = (float*)&vtsm[0][0];
        if (ks == 1) {
            int sb = wq * 2048;
            rss[wq * 64 + lane] = rs;
#pragma unroll
            for (int i = 0; i < 16; i++) ocs[sb + i * 64 + lane] = oacc0[i];
#pragma unroll
            for (int i = 0; i < 16; i++) ocs[sb + (16 + i) * 64 + lane] = oacc1[i];
        }
        __syncthreads();
        if (ks == 0) {
            int sb = wq * 2048;
            rs += rss[wq * 64 + lane];
#pragma unroll
            for (int i = 0; i < 16; i++) oacc0[i] += ocs[sb + i * 64 + lane];
#pragma unroll
            for (int i = 0; i < 16; i++) oacc1[i] += ocs[sb + (16 + i) * 64 + lane];

            float rstot = rs + __shfl_xor(rs, 32, 64);
            _Float16* outb = aout + ((size_t)b * 2048 + q0 + wq * 32) * 512 + h * 64;
#pragma unroll
            for (int r = 0; r < 16; r++) {
                int qi = (r & 3) + 8 * (r >> 2) + 4 * hi;
                float inv = 1.0f / __shfl(rstot, qi, 64);
                outb[(size_t)qi * 512 + l31] = (_Float16)(oacc0[r] * inv);
                outb[(size_t)qi * 512 + 32 + l31] = (_Float16)(oacc1[r] * inv);
            }
        }
        __syncthreads();   // protect LDS scratch before next half's staging
    }
}

// ---------------- K4: output projection, 64x128 tiles (reg-prefetch dbuf) -> f32 ----------------
__global__ __launch_bounds__(256) void gemm_out_kernel(
        const _Float16* __restrict__ A, const _Float16* __restrict__ BT,
        const float* __restrict__ bias, float* __restrict__ out) {
    __shared__ __align__(16) _Float16 Asm[64][72];
    __shared__ __align__(16) _Float16 Bsm[128][72];

    int tid = threadIdx.x;
    int wave = tid >> 6, lane = tid & 63;
    int lrow = lane & 15, quad = lane >> 4;
    int mBase = blockIdx.x * 64, nBase = blockIdx.y * 128;
    int mrow = wave * 16 + lrow;

    const floatx4 fz = {0.f, 0.f, 0.f, 0.f};
    floatx4 acc[8];
    for (int i = 0; i < 8; i++) acc[i] = fz;

    int arow[2], aseg[2], brow[4], bseg[4];
    for (int i = 0; i < 2; i++) { int f = i * 256 + tid; arow[i] = f >> 3; aseg[i] = f & 7; }
    for (int i = 0; i < 4; i++) { int f = i * 256 + tid; brow[i] = f >> 3; bseg[i] = f & 7; }

    half8 areg[2], breg[4];
    for (int i = 0; i < 2; i++)
        areg[i] = *(const half8*)(A + (size_t)(mBase + arow[i]) * 512 + aseg[i] * 8);
    for (int i = 0; i < 4; i++)
        breg[i] = *(const half8*)(BT + (size_t)(nBase + brow[i]) * 512 + bseg[i] * 8);

    for (int kb = 0; kb < 512; kb += 64) {
        for (int i = 0; i < 2; i++) *(half8*)&Asm[arow[i]][aseg[i] * 8] = areg[i];
        for (int i = 0; i < 4; i++) *(half8*)&Bsm[brow[i]][bseg[i] * 8] = breg[i];
        __syncthreads();
        if (kb + 64 < 512) {
            int kn = kb + 64;
            for (int i = 0; i < 2; i++)
                areg[i] = *(const half8*)(A + (size_t)(mBase + arow[i]) * 512 + kn + aseg[i] * 8);
            for (int i = 0; i < 4; i++)
                breg[i] = *(const half8*)(BT + (size_t)(nBase + brow[i]) * 512 + kn + bseg[i] * 8);
        }
        for (int kc = 0; kc < 2; kc++) {
            int ko_ = kc * 32 + quad * 8;
            half8 a = *(const half8*)&Asm[mrow][ko_];
            for (int nt = 0; nt < 8; nt++) {
                half8 b = *(const half8*)&Bsm[nt * 16 + lrow][ko_];
                acc[nt] = __builtin_amdgcn_mfma_f32_16x16x32_f16(a, b, acc[nt], 0, 0, 0);
            }
        }
        __syncthreads();
    }

    for (int nt = 0; nt < 8; nt++) {
        int gc = nBase + nt * 16 + lrow;
        float bb = bias[gc];
        for (int r = 0; r < 4; r++) {
            int gr = mBase + wave * 16 + quad * 4 + r;
            out[(size_t)gr * 512 + gc] = acc[nt][r] + bb;
        }
    }
}

extern "C" void kernel_launch(void* const* d_in, const int* in_sizes, int n_in,
                              void* d_out, int out_size, void* d_ws, size_t ws_size,
                              hipStream_t stream) {
    const float* Q  = (const float*)d_in[0];
    const float* K  = (const float*)d_in[1];
    const float* V  = (const float*)d_in[2];
    const int*   VL = (const int*)d_in[3];
    const float* Wq = (const float*)d_in[4];
    const float* bq = (const float*)d_in[5];
    const float* Wk = (const float*)d_in[6];
    const float* bk = (const float*)d_in[7];
    const float* Wv = (const float*)d_in[8];
    const float* bv = (const float*)d_in[9];
    const float* Wo = (const float*)d_in[10];
    const float* bo = (const float*)d_in[11];

    char* ws = (char*)d_ws;
    _Float16* WT   = (_Float16*)ws;                                  // 2 MiB
    _Float16* qws  = (_Float16*)(ws + (size_t)(2)  * 1024 * 1024);   // 8 MiB [bh][s][hd]
    _Float16* kws  = (_Float16*)(ws + (size_t)(10) * 1024 * 1024);   // 8 MiB [bh][s][hd]
    _Float16* aout = (_Float16*)(ws + (size_t)(18) * 1024 * 1024);   // 8 MiB [8192,512]
    _Float16* vtws = (_Float16*)(ws + (size_t)(26) * 1024 * 1024);   // 8 MiB [bh][hd][s]

    transpose_w_kernel<<<dim3(8, 8, 4), 256, 0, stream>>>(Wq, Wk, Wv, Wo, WT);
    gemm_qkv_kernel<<<dim3(128, 4, 3), 256, 0, stream>>>(Q, K, V, WT, bq, bk, bv, VL, qws, kws, vtws);
    attn_kernel<<<dim3(512, 1, 1), 256, 0, stream>>>(qws, kws, vtws, VL, aout);
    gemm_out_kernel<<<dim3(128, 4, 1), 256, 0, stream>>>(aout, WT + (size_t)3 * 512 * 512, bo, (float*)d_out);
}

// Round 13
// 186.780 us; speedup vs baseline: 1.8801x; 1.0707x over previous
//
#include <hip/hip_runtime.h>
#include <hip/hip_bf16.h>

typedef _Float16 half8 __attribute__((ext_vector_type(8)));
typedef _Float16 half4 __attribute__((ext_vector_type(4)));
typedef _Float16 half2t __attribute__((ext_vector_type(2)));
typedef float floatx4 __attribute__((ext_vector_type(4)));
typedef float floatx16 __attribute__((ext_vector_type(16)));
typedef unsigned int uint2v __attribute__((ext_vector_type(2)));

#define LOG2E 1.44269504088896340736f

__device__ __forceinline__ half8 cvt8r(floatx4 a, floatx4 b) {
    half8 h;
    h[0] = (_Float16)a[0]; h[1] = (_Float16)a[1]; h[2] = (_Float16)a[2]; h[3] = (_Float16)a[3];
    h[4] = (_Float16)b[0]; h[5] = (_Float16)b[1]; h[6] = (_Float16)b[2]; h[7] = (_Float16)b[3];
    return h;
}

union H8U { half8 h; half2t v2[4]; uint2v u[2]; };

__device__ __forceinline__ half2t pk16(float a, float b) {
    return __builtin_bit_cast(half2t, __builtin_amdgcn_cvt_pkrtz(a, b));
}

// ---------------- K1: transpose + convert W (f32 [512x512]) -> WT fp16 [n][k] ----------------
__global__ __launch_bounds__(256) void transpose_w_kernel(
        const float* __restrict__ Wq, const float* __restrict__ Wk,
        const float* __restrict__ Wv, const float* __restrict__ Wo,
        _Float16* __restrict__ out) {
    const float* W = (blockIdx.z == 0) ? Wq : (blockIdx.z == 1) ? Wk : (blockIdx.z == 2) ? Wv : Wo;
    _Float16* o = out + (size_t)blockIdx.z * 512 * 512;
    __shared__ __align__(16) _Float16 t[64][72];
    int r0 = blockIdx.x * 64, c0 = blockIdx.y * 64;
    int tid = threadIdx.x;
    for (int i = 0; i < 2; i++) {
        int f = i * 256 + tid;
        int row = f >> 3, seg = f & 7;
        const float* p = W + (size_t)(r0 + row) * 512 + c0 + seg * 8;
        *(half8*)&t[row][seg * 8] = cvt8r(*(const floatx4*)p, *(const floatx4*)(p + 4));
    }
    __syncthreads();
    for (int i = 0; i < 2; i++) {
        int f = i * 256 + tid;
        int crow = f >> 3, seg = f & 7;
        half8 hv;
        for (int j = 0; j < 8; j++) hv[j] = t[seg * 8 + j][crow];
        *(half8*)(o + (size_t)(c0 + crow) * 512 + r0 + seg * 8) = hv;
    }
}

// ---------------- K2: QKV projection GEMM, 64x128 tiles; dead K/V blocks skipped ----------------
__global__ __launch_bounds__(256) void gemm_qkv_kernel(
        const float* __restrict__ Xq, const float* __restrict__ Xk, const float* __restrict__ Xv,
        const _Float16* __restrict__ WTall,
        const float* __restrict__ bq, const float* __restrict__ bk, const float* __restrict__ bv,
        const int* __restrict__ vlens,
        _Float16* __restrict__ qo, _Float16* __restrict__ ko2, _Float16* __restrict__ vto) {
    int z = blockIdx.z;
    int mBase = blockIdx.x * 64, nBase = blockIdx.y * 128;

    if (z >= 1) {
        int b_ = mBase >> 11, s0 = mBase & 2047;
        int L = vlens[b_];
        if (s0 >= L && !(z == 2 && L == 0)) return;
    }

    const float* X = (z == 0) ? Xq : (z == 1) ? Xk : Xv;
    const _Float16* BT = WTall + (size_t)z * 512 * 512;
    const float* bias = (z == 0) ? bq : (z == 1) ? bk : bv;

    __shared__ __align__(16) _Float16 Asm[64][72];
    __shared__ __align__(16) _Float16 Bsm[128][72];

    int tid = threadIdx.x;
    int wave = tid >> 6, lane = tid & 63;
    int lrow = lane & 15, quad = lane >> 4;
    int mrow = wave * 16 + lrow;

    const floatx4 fz = {0.f, 0.f, 0.f, 0.f};
    floatx4 acc[8];
    for (int i = 0; i < 8; i++) acc[i] = fz;

    int arow[2], aseg[2], brow[4], bseg[4];
    for (int i = 0; i < 2; i++) { int f = i * 256 + tid; arow[i] = f >> 3; aseg[i] = f & 7; }
    for (int i = 0; i < 4; i++) { int f = i * 256 + tid; brow[i] = f >> 3; bseg[i] = f & 7; }

    floatx4 areg[2][2];
    half8 breg[4];
    for (int i = 0; i < 2; i++) {
        const float* pa = X + (size_t)(mBase + arow[i]) * 512 + aseg[i] * 8;
        areg[i][0] = *(const floatx4*)pa;
        areg[i][1] = *(const floatx4*)(pa + 4);
    }
    for (int i = 0; i < 4; i++)
        breg[i] = *(const half8*)(BT + (size_t)(nBase + brow[i]) * 512 + bseg[i] * 8);

    for (int kb = 0; kb < 512; kb += 64) {
        for (int i = 0; i < 2; i++) *(half8*)&Asm[arow[i]][aseg[i] * 8] = cvt8r(areg[i][0], areg[i][1]);
        for (int i = 0; i < 4; i++) *(half8*)&Bsm[brow[i]][bseg[i] * 8] = breg[i];
        __syncthreads();
        if (kb + 64 < 512) {
            int kn = kb + 64;
            for (int i = 0; i < 2; i++) {
                const float* pa = X + (size_t)(mBase + arow[i]) * 512 + kn + aseg[i] * 8;
                areg[i][0] = *(const floatx4*)pa;
                areg[i][1] = *(const floatx4*)(pa + 4);
            }
            for (int i = 0; i < 4; i++)
                breg[i] = *(const half8*)(BT + (size_t)(nBase + brow[i]) * 512 + kn + bseg[i] * 8);
        }
        for (int kc = 0; kc < 2; kc++) {
            int ko_ = kc * 32 + quad * 8;
            half8 a = *(const half8*)&Asm[mrow][ko_];
            for (int nt = 0; nt < 8; nt++) {
                half8 b = *(const half8*)&Bsm[nt * 16 + lrow][ko_];
                acc[nt] = __builtin_amdgcn_mfma_f32_16x16x32_f16(a, b, acc[nt], 0, 0, 0);
            }
        }
        __syncthreads();
    }

    if (z == 2) {
        for (int nt = 0; nt < 8; nt++) {
            int gc = nBase + nt * 16 + lrow;
            float bb = bias[gc];
            int h = gc >> 6, hd = gc & 63;
            int gr = mBase + wave * 16 + quad * 4;
            int b_ = gr >> 11, s = gr & 2047;
            half4 hv;
            for (int r = 0; r < 4; r++) hv[r] = (_Float16)(acc[nt][r] + bb);
            *(half4*)(vto + (((size_t)(b_ * 8 + h) * 64 + hd) * 2048 + s)) = hv;
        }
    } else {
        _Float16* out = (z == 0) ? qo : ko2;
        for (int nt = 0; nt < 8; nt++) {
            int gc = nBase + nt * 16 + lrow;
            float bb = bias[gc];
            int h = gc >> 6, hd = gc & 63;
            for (int r = 0; r < 4; r++) {
                int gr = mBase + wave * 16 + quad * 4 + r;
                int b_ = gr >> 11, s = gr & 2047;
                out[(((size_t)b_ * 8 + h) * 2048 + s) * 64 + hd] = (_Float16)(acc[nt][r] + bb);
            }
        }
    }
}

// ---------------- K3: flash attention v20: r10 base + dual QK chains ----------------
// r10 (49.4 µs) structure restored. Change: both 32-key groups' S-accumulators computed as
// two INDEPENDENT interleaved MFMA chains (halves exposed QK latency at ~1.2 waves/SIMD),
// then per-group softmax+PV. +16 VGPR (~116), still <=128 so 4 blocks x 4 waves/CU cap holds.
__global__ __launch_bounds__(256) void attn_kernel(
        const _Float16* __restrict__ qws, const _Float16* __restrict__ kws,
        const _Float16* __restrict__ vtws, const int* __restrict__ vlens,
        _Float16* __restrict__ aout) {
    int idx = blockIdx.x;
    int b = ((idx & 3) + (idx >> 8)) & 3;
    int h = (idx >> 2) & 7;
    int q0 = ((idx >> 5) & 31) * 64;
    int bh = b * 8 + h;
    int L = vlens[b];
    bool uni = (L == 0);
    int nkt = uni ? 32 : ((L + 63) >> 6);
    int nfull = uni ? 0 : (L >> 6);

    int tid = threadIdx.x;
    int wid = tid >> 6;
    int wq = wid & 1, ks = wid >> 1;
    int lane = tid & 63;
    int l31 = lane & 31, hi = lane >> 5;

    __shared__ __align__(16) _Float16 ksm[2][64 * 64];
    __shared__ __align__(16) _Float16 vtsm[2][64 * 64];

    const _Float16* kbase = kws + (size_t)bh * 2048 * 64;
    const _Float16* vtbase = vtws + (size_t)bh * 64 * 2048;

    half8 qf[4];
    {
        const _Float16* qrow = qws + ((size_t)bh * 2048 + q0 + wq * 32 + l31) * 64;
#pragma unroll
        for (int kc = 0; kc < 4; kc++) {
            qf[kc] = *(const half8*)(qrow + kc * 16 + hi * 8);
            qf[kc] = qf[kc] * (_Float16)(0.125f * LOG2E);
        }
    }

    floatx16 oacc0, oacc1;
#pragma unroll
    for (int i = 0; i < 16; i++) { oacc0[i] = 0.f; oacc1[i] = 0.f; }
    float rs = 0.f;

    int htid = tid & 127;
    int tt = tid >> 7;
    int seg = htid & 7;
    int trow = htid >> 3;
    int xr = (l31 & 15) << 3;
    char* ksmB = (char*)&ksm[tt][0];
    char* vsmB = (char*)&vtsm[tt][0];

    half8 kreg[4], vreg[4];
    if (tt < nkt) {
        const _Float16* kp = kbase + (size_t)tt * 4096;
        const _Float16* vp = vtbase + tt * 64;
#pragma unroll
        for (int i = 0; i < 4; i++) {
            int row = i * 16 + trow;
            kreg[i] = *(const half8*)(kp + row * 64 + seg * 8);
            vreg[i] = *(const half8*)(vp + (size_t)row * 2048 + seg * 8);
        }
    }

    for (int kt2 = 0; kt2 < nkt; kt2 += 2) {
        if (kt2 + tt < nkt) {
#pragma unroll
            for (int i = 0; i < 4; i++) {
                int row = i * 16 + trow;
                int wo = row * 128 + ((seg * 16) ^ ((row & 15) << 3));
                H8U kv, vv;
                kv.h = kreg[i]; vv.h = vreg[i];
                *(uint2v*)(ksmB + wo) = kv.u[0];
                *(uint2v*)(ksmB + (wo ^ 8)) = kv.u[1];
                *(uint2v*)(vsmB + wo) = vv.u[0];
                *(uint2v*)(vsmB + (wo ^ 8)) = vv.u[1];
            }
        }
        __syncthreads();
        int nxt = kt2 + 2 + tt;
        if (nxt < nkt) {
            const _Float16* kp = kbase + (size_t)nxt * 4096;
            const _Float16* vp = vtbase + (size_t)nxt * 64;
#pragma unroll
            for (int i = 0; i < 4; i++) {
                int row = i * 16 + trow;
                kreg[i] = *(const half8*)(kp + row * 64 + seg * 8);
                vreg[i] = *(const half8*)(vp + (size_t)row * 2048 + seg * 8);
            }
        }

        int kt = kt2 + ks;
        if (kt < nkt) {
            // ---- QK: two independent MFMA chains (t=0, t=1), interleaved per kc ----
            floatx16 sacc0, sacc1;
#pragma unroll
            for (int i = 0; i < 16; i++) { sacc0[i] = 0.f; sacc1[i] = 0.f; }
            int rb0 = l31 * 128;
            int rb1 = (32 + l31) * 128;
#pragma unroll
            for (int kc = 0; kc < 4; kc++) {
                int co = (kc * 32 + hi * 16) ^ xr;
                H8U kf0, kf1;
                kf0.u[0] = *(const uint2v*)(ksmB + rb0 + co);
                kf0.u[1] = *(const uint2v*)(ksmB + ((rb0 + co) ^ 8));
                kf1.u[0] = *(const uint2v*)(ksmB + rb1 + co);
                kf1.u[1] = *(const uint2v*)(ksmB + ((rb1 + co) ^ 8));
                sacc0 = __builtin_amdgcn_mfma_f32_32x32x16_f16(kf0.h, qf[kc], sacc0, 0, 0, 0);
                sacc1 = __builtin_amdgcn_mfma_f32_32x32x16_f16(kf1.h, qf[kc], sacc1, 0, 0, 0);
            }

            // ---- per-group softmax + PV ----
#pragma unroll
            for (int t = 0; t < 2; t++) {
                const floatx16& sacc = (t == 0) ? sacc0 : sacc1;
                float p[16];
                if (kt < nfull) {
#pragma unroll
                    for (int r = 0; r < 16; r++) p[r] = __builtin_amdgcn_exp2f(sacc[r]);
                } else {
                    int kb0 = kt * 64 + t * 32 + 4 * hi;
#pragma unroll
                    for (int r = 0; r < 16; r++) {
                        int key = kb0 + (r & 3) + 8 * (r >> 2);
                        p[r] = uni ? 1.0f : ((key < L) ? __builtin_amdgcn_exp2f(sacc[r]) : 0.0f);
                    }
                }
                rs += (((p[0] + p[1]) + (p[2] + p[3])) + ((p[4] + p[5]) + (p[6] + p[7])))
                    + (((p[8] + p[9]) + (p[10] + p[11])) + ((p[12] + p[13]) + (p[14] + p[15])));

#pragma unroll
                for (int s2 = 0; s2 < 2; s2++) {
                    int s = t * 2 + s2;
                    H8U pa;
#pragma unroll
                    for (int jj = 0; jj < 4; jj++)
                        pa.v2[jj] = pk16(p[s2 * 8 + jj * 2], p[s2 * 8 + jj * 2 + 1]);
                    int cb = (s * 32 + hi * 8) ^ xr;
                    {
                        int off = l31 * 128 + cb;
                        H8U vf;
                        vf.u[0] = *(const uint2v*)(vsmB + off);
                        vf.u[1] = *(const uint2v*)(vsmB + (off ^ 16));
                        oacc0 = __builtin_amdgcn_mfma_f32_32x32x16_f16(pa.h, vf.h, oacc0, 0, 0, 0);
                    }
                    {
                        int off = (32 + l31) * 128 + cb;
                        H8U vf;
                        vf.u[0] = *(const uint2v*)(vsmB + off);
                        vf.u[1] = *(const uint2v*)(vsmB + (off ^ 16));
                        oacc1 = __builtin_amdgcn_mfma_f32_32x32x16_f16(pa.h, vf.h, oacc1, 0, 0, 0);
                    }
                }
            }
        }
        __syncthreads();
    }

    float* ocs = (float*)&ksm[0][0];
    float* rss = (float*)&vtsm[0][0];
    if (ks == 1) {
        int sb = wq * 2048;
        rss[wq * 64 + lane] = rs;
#pragma unroll
        for (int i = 0; i < 16; i++) ocs[sb + i * 64 + lane] = oacc0[i];
#pragma unroll
        for (int i = 0; i < 16; i++) ocs[sb + (16 + i) * 64 + lane] = oacc1[i];
    }
    __syncthreads();
    if (ks == 0) {
        int sb = wq * 2048;
        rs += rss[wq * 64 + lane];
#pragma unroll
        for (int i = 0; i < 16; i++) oacc0[i] += ocs[sb + i * 64 + lane];
#pragma unroll
        for (int i = 0; i < 16; i++) oacc1[i] += ocs[sb + (16 + i) * 64 + lane];

        float rstot = rs + __shfl_xor(rs, 32, 64);
        _Float16* outb = aout + ((size_t)b * 2048 + q0 + wq * 32) * 512 + h * 64;
#pragma unroll
        for (int r = 0; r < 16; r++) {
            int qi = (r & 3) + 8 * (r >> 2) + 4 * hi;
            float inv = 1.0f / __shfl(rstot, qi, 64);
            outb[(size_t)qi * 512 + l31] = (_Float16)(oacc0[r] * inv);
            outb[(size_t)qi * 512 + 32 + l31] = (_Float16)(oacc1[r] * inv);
        }
    }
}

// ---------------- K4: output projection, 64x128 tiles (reg-prefetch dbuf) -> f32 ----------------
__global__ __launch_bounds__(256) void gemm_out_kernel(
        const _Float16* __restrict__ A, const _Float16* __restrict__ BT,
        const float* __restrict__ bias, float* __restrict__ out) {
    __shared__ __align__(16) _Float16 Asm[64][72];
    __shared__ __align__(16) _Float16 Bsm[128][72];

    int tid = threadIdx.x;
    int wave = tid >> 6, lane = tid & 63;
    int lrow = lane & 15, quad = lane >> 4;
    int mBase = blockIdx.x * 64, nBase = blockIdx.y * 128;
    int mrow = wave * 16 + lrow;

    const floatx4 fz = {0.f, 0.f, 0.f, 0.f};
    floatx4 acc[8];
    for (int i = 0; i < 8; i++) acc[i] = fz;

    int arow[2], aseg[2], brow[4], bseg[4];
    for (int i = 0; i < 2; i++) { int f = i * 256 + tid; arow[i] = f >> 3; aseg[i] = f & 7; }
    for (int i = 0; i < 4; i++) { int f = i * 256 + tid; brow[i] = f >> 3; bseg[i] = f & 7; }

    half8 areg[2], breg[4];
    for (int i = 0; i < 2; i++)
        areg[i] = *(const half8*)(A + (size_t)(mBase + arow[i]) * 512 + aseg[i] * 8);
    for (int i = 0; i < 4; i++)
        breg[i] = *(const half8*)(BT + (size_t)(nBase + brow[i]) * 512 + bseg[i] * 8);

    for (int kb = 0; kb < 512; kb += 64) {
        for (int i = 0; i < 2; i++) *(half8*)&Asm[arow[i]][aseg[i] * 8] = areg[i];
        for (int i = 0; i < 4; i++) *(half8*)&Bsm[brow[i]][bseg[i] * 8] = breg[i];
        __syncthreads();
        if (kb + 64 < 512) {
            int kn = kb + 64;
            for (int i = 0; i < 2; i++)
                areg[i] = *(const half8*)(A + (size_t)(mBase + arow[i]) * 512 + kn + aseg[i] * 8);
            for (int i = 0; i < 4; i++)
                breg[i] = *(const half8*)(BT + (size_t)(nBase + brow[i]) * 512 + kn + bseg[i] * 8);
        }
        for (int kc = 0; kc < 2; kc++) {
            int ko_ = kc * 32 + quad * 8;
            half8 a = *(const half8*)&Asm[mrow][ko_];
            for (int nt = 0; nt < 8; nt++) {
                half8 b = *(const half8*)&Bsm[nt * 16 + lrow][ko_];
                acc[nt] = __builtin_amdgcn_mfma_f32_16x16x32_f16(a, b, acc[nt], 0, 0, 0);
            }
        }
        __syncthreads();
    }

    for (int nt = 0; nt < 8; nt++) {
        int gc = nBase + nt * 16 + lrow;
        float bb = bias[gc];
        for (int r = 0; r < 4; r++) {
            int gr = mBase + wave * 16 + quad * 4 + r;
            out[(size_t)gr * 512 + gc] = acc[nt][r] + bb;
        }
    }
}

extern "C" void kernel_launch(void* const* d_in, const int* in_sizes, int n_in,
                              void* d_out, int out_size, void* d_ws, size_t ws_size,
                              hipStream_t stream) {
    const float* Q  = (const float*)d_in[0];
    const float* K  = (const float*)d_in[1];
    const float* V  = (const float*)d_in[2];
    const int*   VL = (const int*)d_in[3];
    const float* Wq = (const float*)d_in[4];
    const float* bq = (const float*)d_in[5];
    const float* Wk = (const float*)d_in[6];
    const float* bk = (const float*)d_in[7];
    const float* Wv = (const float*)d_in[8];
    const float* bv = (const float*)d_in[9];
    const float* Wo = (const float*)d_in[10];
    const float* bo = (const float*)d_in[11];

    char* ws = (char*)d_ws;
    _Float16* WT   = (_Float16*)ws;                                  // 2 MiB
    _Float16* qws  = (_Float16*)(ws + (size_t)(2)  * 1024 * 1024);   // 8 MiB [bh][s][hd]
    _Float16* kws  = (_Float16*)(ws + (size_t)(10) * 1024 * 1024);   // 8 MiB [bh][s][hd]
    _Float16* aout = (_Float16*)(ws + (size_t)(18) * 1024 * 1024);   // 8 MiB [8192,512]
    _Float16* vtws = (_Float16*)(ws + (size_t)(26) * 1024 * 1024);   // 8 MiB [bh][hd][s]

    transpose_w_kernel<<<dim3(8, 8, 4), 256, 0, stream>>>(Wq, Wk, Wv, Wo, WT);
    gemm_qkv_kernel<<<dim3(128, 4, 3), 256, 0, stream>>>(Q, K, V, WT, bq, bk, bv, VL, qws, kws, vtws);
    attn_kernel<<<dim3(1024, 1, 1), 256, 0, stream>>>(qws, kws, vtws, VL, aout);
    gemm_out_kernel<<<dim3(128, 4, 1), 256, 0, stream>>>(aout, WT + (size_t)3 * 512 * 512, bo, (float*)d_out);
}

// Round 14
// 184.860 us; speedup vs baseline: 1.8996x; 1.0104x over previous
//
#include <hip/hip_runtime.h>
#include <hip/hip_bf16.h>

typedef _Float16 half8 __attribute__((ext_vector_type(8)));
typedef _Float16 half4 __attribute__((ext_vector_type(4)));
typedef _Float16 half2t __attribute__((ext_vector_type(2)));
typedef float floatx4 __attribute__((ext_vector_type(4)));
typedef float floatx16 __attribute__((ext_vector_type(16)));
typedef unsigned int uint2v __attribute__((ext_vector_type(2)));

#define LOG2E 1.44269504088896340736f

__device__ __forceinline__ half8 cvt8r(floatx4 a, floatx4 b) {
    half8 h;
    h[0] = (_Float16)a[0]; h[1] = (_Float16)a[1]; h[2] = (_Float16)a[2]; h[3] = (_Float16)a[3];
    h[4] = (_Float16)b[0]; h[5] = (_Float16)b[1]; h[6] = (_Float16)b[2]; h[7] = (_Float16)b[3];
    return h;
}

union H8U { half8 h; half2t v2[4]; uint2v u[2]; };

__device__ __forceinline__ half2t pk16(float a, float b) {
    return __builtin_bit_cast(half2t, __builtin_amdgcn_cvt_pkrtz(a, b));
}

// ---------------- K1: transpose + convert W (f32 [512x512]) -> WT fp16 [n][k] ----------------
__global__ __launch_bounds__(256) void transpose_w_kernel(
        const float* __restrict__ Wq, const float* __restrict__ Wk,
        const float* __restrict__ Wv, const float* __restrict__ Wo,
        _Float16* __restrict__ out) {
    const float* W = (blockIdx.z == 0) ? Wq : (blockIdx.z == 1) ? Wk : (blockIdx.z == 2) ? Wv : Wo;
    _Float16* o = out + (size_t)blockIdx.z * 512 * 512;
    __shared__ __align__(16) _Float16 t[64][72];
    int r0 = blockIdx.x * 64, c0 = blockIdx.y * 64;
    int tid = threadIdx.x;
    for (int i = 0; i < 2; i++) {
        int f = i * 256 + tid;
        int row = f >> 3, seg = f & 7;
        const float* p = W + (size_t)(r0 + row) * 512 + c0 + seg * 8;
        *(half8*)&t[row][seg * 8] = cvt8r(*(const floatx4*)p, *(const floatx4*)(p + 4));
    }
    __syncthreads();
    for (int i = 0; i < 2; i++) {
        int f = i * 256 + tid;
        int crow = f >> 3, seg = f & 7;
        half8 hv;
        for (int j = 0; j < 8; j++) hv[j] = t[seg * 8 + j][crow];
        *(half8*)(o + (size_t)(c0 + crow) * 512 + r0 + seg * 8) = hv;
    }
}

// ---------------- K2: QKV projection GEMM, 64x128 tiles; dead K/V blocks skipped ----------------
__global__ __launch_bounds__(256) void gemm_qkv_kernel(
        const float* __restrict__ Xq, const float* __restrict__ Xk, const float* __restrict__ Xv,
        const _Float16* __restrict__ WTall,
        const float* __restrict__ bq, const float* __restrict__ bk, const float* __restrict__ bv,
        const int* __restrict__ vlens,
        _Float16* __restrict__ qo, _Float16* __restrict__ ko2, _Float16* __restrict__ vto) {
    int z = blockIdx.z;
    int mBase = blockIdx.x * 64, nBase = blockIdx.y * 128;

    if (z >= 1) {
        int b_ = mBase >> 11, s0 = mBase & 2047;
        int L = vlens[b_];
        if (s0 >= L && !(z == 2 && L == 0)) return;
    }

    const float* X = (z == 0) ? Xq : (z == 1) ? Xk : Xv;
    const _Float16* BT = WTall + (size_t)z * 512 * 512;
    const float* bias = (z == 0) ? bq : (z == 1) ? bk : bv;

    __shared__ __align__(16) _Float16 Asm[64][72];
    __shared__ __align__(16) _Float16 Bsm[128][72];

    int tid = threadIdx.x;
    int wave = tid >> 6, lane = tid & 63;
    int lrow = lane & 15, quad = lane >> 4;
    int mrow = wave * 16 + lrow;

    const floatx4 fz = {0.f, 0.f, 0.f, 0.f};
    floatx4 acc[8];
    for (int i = 0; i < 8; i++) acc[i] = fz;

    int arow[2], aseg[2], brow[4], bseg[4];
    for (int i = 0; i < 2; i++) { int f = i * 256 + tid; arow[i] = f >> 3; aseg[i] = f & 7; }
    for (int i = 0; i < 4; i++) { int f = i * 256 + tid; brow[i] = f >> 3; bseg[i] = f & 7; }

    floatx4 areg[2][2];
    half8 breg[4];
    for (int i = 0; i < 2; i++) {
        const float* pa = X + (size_t)(mBase + arow[i]) * 512 + aseg[i] * 8;
        areg[i][0] = *(const floatx4*)pa;
        areg[i][1] = *(const floatx4*)(pa + 4);
    }
    for (int i = 0; i < 4; i++)
        breg[i] = *(const half8*)(BT + (size_t)(nBase + brow[i]) * 512 + bseg[i] * 8);

    for (int kb = 0; kb < 512; kb += 64) {
        for (int i = 0; i < 2; i++) *(half8*)&Asm[arow[i]][aseg[i] * 8] = cvt8r(areg[i][0], areg[i][1]);
        for (int i = 0; i < 4; i++) *(half8*)&Bsm[brow[i]][bseg[i] * 8] = breg[i];
        __syncthreads();
        if (kb + 64 < 512) {
            int kn = kb + 64;
            for (int i = 0; i < 2; i++) {
                const float* pa = X + (size_t)(mBase + arow[i]) * 512 + kn + aseg[i] * 8;
                areg[i][0] = *(const floatx4*)pa;
                areg[i][1] = *(const floatx4*)(pa + 4);
            }
            for (int i = 0; i < 4; i++)
                breg[i] = *(const half8*)(BT + (size_t)(nBase + brow[i]) * 512 + kn + bseg[i] * 8);
        }
        for (int kc = 0; kc < 2; kc++) {
            int ko_ = kc * 32 + quad * 8;
            half8 a = *(const half8*)&Asm[mrow][ko_];
            for (int nt = 0; nt < 8; nt++) {
                half8 b = *(const half8*)&Bsm[nt * 16 + lrow][ko_];
                acc[nt] = __builtin_amdgcn_mfma_f32_16x16x32_f16(a, b, acc[nt], 0, 0, 0);
            }
        }
        __syncthreads();
    }

    if (z == 2) {
        for (int nt = 0; nt < 8; nt++) {
            int gc = nBase + nt * 16 + lrow;
            float bb = bias[gc];
            int h = gc >> 6, hd = gc & 63;
            int gr = mBase + wave * 16 + quad * 4;
            int b_ = gr >> 11, s = gr & 2047;
            half4 hv;
            for (int r = 0; r < 4; r++) hv[r] = (_Float16)(acc[nt][r] + bb);
            *(half4*)(vto + (((size_t)(b_ * 8 + h) * 64 + hd) * 2048 + s)) = hv;
        }
    } else {
        _Float16* out = (z == 0) ? qo : ko2;
        for (int nt = 0; nt < 8; nt++) {
            int gc = nBase + nt * 16 + lrow;
            float bb = bias[gc];
            int h = gc >> 6, hd = gc & 63;
            for (int r = 0; r < 4; r++) {
                int gr = mBase + wave * 16 + quad * 4 + r;
                int b_ = gr >> 11, s = gr & 2047;
                out[(((size_t)b_ * 8 + h) * 2048 + s) * 64 + hd] = (_Float16)(acc[nt][r] + bb);
            }
        }
    }
}

// ---------------- K3: flash attention v18 (r10 exact, best measured 49.4 µs) ----------------
// BM=64, 4 waves (2 wq x 2 ks), dbuf LDS, in-LDS key-split combine, PV VALU diet
// (pk16 packed cvt, tree rowsum, raw exp2). Phase split (r9): staging 12.6 / QK+SM 16.4 / PV ~20.
__global__ __launch_bounds__(256) void attn_kernel(
        const _Float16* __restrict__ qws, const _Float16* __restrict__ kws,
        const _Float16* __restrict__ vtws, const int* __restrict__ vlens,
        _Float16* __restrict__ aout) {
    int idx = blockIdx.x;
    int b = ((idx & 3) + (idx >> 8)) & 3;
    int h = (idx >> 2) & 7;
    int q0 = ((idx >> 5) & 31) * 64;
    int bh = b * 8 + h;
    int L = vlens[b];
    bool uni = (L == 0);
    int nkt = uni ? 32 : ((L + 63) >> 6);
    int nfull = uni ? 0 : (L >> 6);

    int tid = threadIdx.x;
    int wid = tid >> 6;
    int wq = wid & 1, ks = wid >> 1;
    int lane = tid & 63;
    int l31 = lane & 31, hi = lane >> 5;

    __shared__ __align__(16) _Float16 ksm[2][64 * 64];
    __shared__ __align__(16) _Float16 vtsm[2][64 * 64];

    const _Float16* kbase = kws + (size_t)bh * 2048 * 64;
    const _Float16* vtbase = vtws + (size_t)bh * 64 * 2048;

    half8 qf[4];
    {
        const _Float16* qrow = qws + ((size_t)bh * 2048 + q0 + wq * 32 + l31) * 64;
#pragma unroll
        for (int kc = 0; kc < 4; kc++) {
            qf[kc] = *(const half8*)(qrow + kc * 16 + hi * 8);
            qf[kc] = qf[kc] * (_Float16)(0.125f * LOG2E);
        }
    }

    floatx16 oacc0, oacc1;
#pragma unroll
    for (int i = 0; i < 16; i++) { oacc0[i] = 0.f; oacc1[i] = 0.f; }
    float rs = 0.f;

    int htid = tid & 127;
    int tt = tid >> 7;
    int seg = htid & 7;
    int trow = htid >> 3;
    int xr = (l31 & 15) << 3;
    char* ksmB = (char*)&ksm[tt][0];
    char* vsmB = (char*)&vtsm[tt][0];

    half8 kreg[4], vreg[4];
    if (tt < nkt) {
        const _Float16* kp = kbase + (size_t)tt * 4096;
        const _Float16* vp = vtbase + tt * 64;
#pragma unroll
        for (int i = 0; i < 4; i++) {
            int row = i * 16 + trow;
            kreg[i] = *(const half8*)(kp + row * 64 + seg * 8);
            vreg[i] = *(const half8*)(vp + (size_t)row * 2048 + seg * 8);
        }
    }

    for (int kt2 = 0; kt2 < nkt; kt2 += 2) {
        if (kt2 + tt < nkt) {
#pragma unroll
            for (int i = 0; i < 4; i++) {
                int row = i * 16 + trow;
                int wo = row * 128 + ((seg * 16) ^ ((row & 15) << 3));
                H8U kv, vv;
                kv.h = kreg[i]; vv.h = vreg[i];
                *(uint2v*)(ksmB + wo) = kv.u[0];
                *(uint2v*)(ksmB + (wo ^ 8)) = kv.u[1];
                *(uint2v*)(vsmB + wo) = vv.u[0];
                *(uint2v*)(vsmB + (wo ^ 8)) = vv.u[1];
            }
        }
        __syncthreads();
        int nxt = kt2 + 2 + tt;
        if (nxt < nkt) {
            const _Float16* kp = kbase + (size_t)nxt * 4096;
            const _Float16* vp = vtbase + (size_t)nxt * 64;
#pragma unroll
            for (int i = 0; i < 4; i++) {
                int row = i * 16 + trow;
                kreg[i] = *(const half8*)(kp + row * 64 + seg * 8);
                vreg[i] = *(const half8*)(vp + (size_t)row * 2048 + seg * 8);
            }
        }

        int kt = kt2 + ks;
        if (kt < nkt) {
#pragma unroll
            for (int t = 0; t < 2; t++) {
                floatx16 sacc;
#pragma unroll
                for (int i = 0; i < 16; i++) sacc[i] = 0.f;
                int rbase = (t * 32 + l31) * 128;
#pragma unroll
                for (int kc = 0; kc < 4; kc++) {
                    int off = rbase + ((kc * 32 + hi * 16) ^ xr);
                    H8U kf;
                    kf.u[0] = *(const uint2v*)(ksmB + off);
                    kf.u[1] = *(const uint2v*)(ksmB + (off ^ 8));
                    sacc = __builtin_amdgcn_mfma_f32_32x32x16_f16(kf.h, qf[kc], sacc, 0, 0, 0);
                }

                float p[16];
                if (kt < nfull) {
#pragma unroll
                    for (int r = 0; r < 16; r++) p[r] = __builtin_amdgcn_exp2f(sacc[r]);
                } else {
                    int kb0 = kt * 64 + t * 32 + 4 * hi;
#pragma unroll
                    for (int r = 0; r < 16; r++) {
                        int key = kb0 + (r & 3) + 8 * (r >> 2);
                        p[r] = uni ? 1.0f : ((key < L) ? __builtin_amdgcn_exp2f(sacc[r]) : 0.0f);
                    }
                }
                rs += (((p[0] + p[1]) + (p[2] + p[3])) + ((p[4] + p[5]) + (p[6] + p[7])))
                    + (((p[8] + p[9]) + (p[10] + p[11])) + ((p[12] + p[13]) + (p[14] + p[15])));

#pragma unroll
                for (int s2 = 0; s2 < 2; s2++) {
                    int s = t * 2 + s2;
                    H8U pa;
#pragma unroll
                    for (int jj = 0; jj < 4; jj++)
                        pa.v2[jj] = pk16(p[s2 * 8 + jj * 2], p[s2 * 8 + jj * 2 + 1]);
                    int cb = (s * 32 + hi * 8) ^ xr;
                    {
                        int off = l31 * 128 + cb;
                        H8U vf;
                        vf.u[0] = *(const uint2v*)(vsmB + off);
                        vf.u[1] = *(const uint2v*)(vsmB + (off ^ 16));
                        oacc0 = __builtin_amdgcn_mfma_f32_32x32x16_f16(pa.h, vf.h, oacc0, 0, 0, 0);
                    }
                    {
                        int off = (32 + l31) * 128 + cb;
                        H8U vf;
                        vf.u[0] = *(const uint2v*)(vsmB + off);
                        vf.u[1] = *(const uint2v*)(vsmB + (off ^ 16));
                        oacc1 = __builtin_amdgcn_mfma_f32_32x32x16_f16(pa.h, vf.h, oacc1, 0, 0, 0);
                    }
                }
            }
        }
        __syncthreads();
    }

    float* ocs = (float*)&ksm[0][0];
    float* rss = (float*)&vtsm[0][0];
    if (ks == 1) {
        int sb = wq * 2048;
        rss[wq * 64 + lane] = rs;
#pragma unroll
        for (int i = 0; i < 16; i++) ocs[sb + i * 64 + lane] = oacc0[i];
#pragma unroll
        for (int i = 0; i < 16; i++) ocs[sb + (16 + i) * 64 + lane] = oacc1[i];
    }
    __syncthreads();
    if (ks == 0) {
        int sb = wq * 2048;
        rs += rss[wq * 64 + lane];
#pragma unroll
        for (int i = 0; i < 16; i++) oacc0[i] += ocs[sb + i * 64 + lane];
#pragma unroll
        for (int i = 0; i < 16; i++) oacc1[i] += ocs[sb + (16 + i) * 64 + lane];

        float rstot = rs + __shfl_xor(rs, 32, 64);
        _Float16* outb = aout + ((size_t)b * 2048 + q0 + wq * 32) * 512 + h * 64;
#pragma unroll
        for (int r = 0; r < 16; r++) {
            int qi = (r & 3) + 8 * (r >> 2) + 4 * hi;
            float inv = 1.0f / __shfl(rstot, qi, 64);
            outb[(size_t)qi * 512 + l31] = (_Float16)(oacc0[r] * inv);
            outb[(size_t)qi * 512 + 32 + l31] = (_Float16)(oacc1[r] * inv);
        }
    }
}

// ---------------- K4: output projection, 64x128 tiles (reg-prefetch dbuf) -> f32 ----------------
__global__ __launch_bounds__(256) void gemm_out_kernel(
        const _Float16* __restrict__ A, const _Float16* __restrict__ BT,
        const float* __restrict__ bias, float* __restrict__ out) {
    __shared__ __align__(16) _Float16 Asm[64][72];
    __shared__ __align__(16) _Float16 Bsm[128][72];

    int tid = threadIdx.x;
    int wave = tid >> 6, lane = tid & 63;
    int lrow = lane & 15, quad = lane >> 4;
    int mBase = blockIdx.x * 64, nBase = blockIdx.y * 128;
    int mrow = wave * 16 + lrow;

    const floatx4 fz = {0.f, 0.f, 0.f, 0.f};
    floatx4 acc[8];
    for (int i = 0; i < 8; i++) acc[i] = fz;

    int arow[2], aseg[2], brow[4], bseg[4];
    for (int i = 0; i < 2; i++) { int f = i * 256 + tid; arow[i] = f >> 3; aseg[i] = f & 7; }
    for (int i = 0; i < 4; i++) { int f = i * 256 + tid; brow[i] = f >> 3; bseg[i] = f & 7; }

    half8 areg[2], breg[4];
    for (int i = 0; i < 2; i++)
        areg[i] = *(const half8*)(A + (size_t)(mBase + arow[i]) * 512 + aseg[i] * 8);
    for (int i = 0; i < 4; i++)
        breg[i] = *(const half8*)(BT + (size_t)(nBase + brow[i]) * 512 + bseg[i] * 8);

    for (int kb = 0; kb < 512; kb += 64) {
        for (int i = 0; i < 2; i++) *(half8*)&Asm[arow[i]][aseg[i] * 8] = areg[i];
        for (int i = 0; i < 4; i++) *(half8*)&Bsm[brow[i]][bseg[i] * 8] = breg[i];
        __syncthreads();
        if (kb + 64 < 512) {
            int kn = kb + 64;
            for (int i = 0; i < 2; i++)
                areg[i] = *(const half8*)(A + (size_t)(mBase + arow[i]) * 512 + kn + aseg[i] * 8);
            for (int i = 0; i < 4; i++)
                breg[i] = *(const half8*)(BT + (size_t)(nBase + brow[i]) * 512 + kn + bseg[i] * 8);
        }
        for (int kc = 0; kc < 2; kc++) {
            int ko_ = kc * 32 + quad * 8;
            half8 a = *(const half8*)&Asm[mrow][ko_];
            for (int nt = 0; nt < 8; nt++) {
                half8 b = *(const half8*)&Bsm[nt * 16 + lrow][ko_];
                acc[nt] = __builtin_amdgcn_mfma_f32_16x16x32_f16(a, b, acc[nt], 0, 0, 0);
            }
        }
        __syncthreads();
    }

    for (int nt = 0; nt < 8; nt++) {
        int gc = nBase + nt * 16 + lrow;
        float bb = bias[gc];
        for (int r = 0; r < 4; r++) {
            int gr = mBase + wave * 16 + quad * 4 + r;
            out[(size_t)gr * 512 + gc] = acc[nt][r] + bb;
        }
    }
}

extern "C" void kernel_launch(void* const* d_in, const int* in_sizes, int n_in,
                              void* d_out, int out_size, void* d_ws, size_t ws_size,
                              hipStream_t stream) {
    const float* Q  = (const float*)d_in[0];
    const float* K  = (const float*)d_in[1];
    const float* V  = (const float*)d_in[2];
    const int*   VL = (const int*)d_in[3];
    const float* Wq = (const float*)d_in[4];
    const float* bq = (const float*)d_in[5];
    const float* Wk = (const float*)d_in[6];
    const float* bk = (const float*)d_in[7];
    const float* Wv = (const float*)d_in[8];
    const float* bv = (const float*)d_in[9];
    const float* Wo = (const float*)d_in[10];
    const float* bo = (const float*)d_in[11];

    char* ws = (char*)d_ws;
    _Float16* WT   = (_Float16*)ws;                                  // 2 MiB
    _Float16* qws  = (_Float16*)(ws + (size_t)(2)  * 1024 * 1024);   // 8 MiB [bh][s][hd]
    _Float16* kws  = (_Float16*)(ws + (size_t)(10) * 1024 * 1024);   // 8 MiB [bh][s][hd]
    _Float16* aout = (_Float16*)(ws + (size_t)(18) * 1024 * 1024);   // 8 MiB [8192,512]
    _Float16* vtws = (_Float16*)(ws + (size_t)(26) * 1024 * 1024);   // 8 MiB [bh][hd][s]

    transpose_w_kernel<<<dim3(8, 8, 4), 256, 0, stream>>>(Wq, Wk, Wv, Wo, WT);
    gemm_qkv_kernel<<<dim3(128, 4, 3), 256, 0, stream>>>(Q, K, V, WT, bq, bk, bv, VL, qws, kws, vtws);
    attn_kernel<<<dim3(1024, 1, 1), 256, 0, stream>>>(qws, kws, vtws, VL, aout);
    gemm_out_kernel<<<dim3(128, 4, 1), 256, 0, stream>>>(aout, WT + (size_t)3 * 512 * 512, bo, (float*)d_out);
}